// Round 1
// baseline (2343.422 us; speedup 1.0000x reference)
//
#include <hip/hip_runtime.h>
#include <hip/hip_bf16.h>

typedef float v4 __attribute__((ext_vector_type(4)));

__device__ __forceinline__ unsigned encf(float x) {
    unsigned b = __float_as_uint(x);
    return (b & 0x80000000u) ? ~b : (b | 0x80000000u);
}
__device__ __forceinline__ float decf(unsigned e) {
    return __uint_as_float((e & 0x80000000u) ? (e ^ 0x80000000u) : ~e);
}

// h = relu(x @ embed_w + embed_b); x: [N,20], w: [20,128]
__global__ __launch_bounds__(256) void k_embed(const float* __restrict__ x,
                                               const float* __restrict__ w,
                                               const float* __restrict__ b,
                                               float* __restrict__ h, int n) {
    int idx = blockIdx.x * 256 + threadIdx.x;
    if (idx >= n * 128) return;
    int node = idx >> 7, j = idx & 127;
    float acc = b[j];
#pragma unroll
    for (int k = 0; k < 20; ++k) acc += x[node * 20 + k] * w[k * 128 + j];
    h[idx] = fmaxf(acc, 0.f);
}

__global__ __launch_bounds__(256) void k_zero(float* __restrict__ out_acc,
                                              float* __restrict__ denom,
                                              unsigned* __restrict__ m_enc, int n) {
    int idx = blockIdx.x * 256 + threadIdx.x;
    if (idx < n * 128) out_acc[idx] = 0.f;
    if (idx < n * 4) { denom[idx] = 0.f; m_enc[idx] = 0u; }
}

// out[n][j] = sum_k in[n][k]*W[k][j] (+bias). Optionally per-head alpha dots.
template <bool ALPHAS, bool BIAS>
__global__ __launch_bounds__(256) void k_gemm128(
    const float* __restrict__ in, const float* __restrict__ W,
    const float* __restrict__ bias, float* __restrict__ out,
    const float* __restrict__ avec_src, const float* __restrict__ avec_dst,
    float* __restrict__ asrc, float* __restrict__ adst, int nn) {
    __shared__ float Ws[128 * 128];
    __shared__ float rowbuf[32][128];
    int tid = threadIdx.x;
    const v4* W4 = (const v4*)W;
    v4* Ws4 = (v4*)Ws;
    for (int i = tid; i < 4096; i += 256) Ws4[i] = W4[i];
    int row0 = blockIdx.x * 32;
    for (int i = tid; i < 1024; i += 256) {
        int r = i >> 5, c4 = i & 31;
        int gr = row0 + r;
        v4 v = {0.f, 0.f, 0.f, 0.f};
        if (gr < nn) v = ((const v4*)in)[(size_t)gr * 32 + c4];
        ((v4*)&rowbuf[r][0])[c4] = v;
    }
    __syncthreads();
    int rg = tid >> 5;   // 0..7 -> rows rg*4..rg*4+3
    int cg = tid & 31;   // cols cg*4..cg*4+3
    float acc[4][4] = {};
    for (int k = 0; k < 128; k += 4) {
        v4 wv[4], rv[4];
#pragma unroll
        for (int kk = 0; kk < 4; ++kk) wv[kk] = *(const v4*)&Ws[(k + kk) * 128 + cg * 4];
#pragma unroll
        for (int r = 0; r < 4; ++r) rv[r] = *(const v4*)&rowbuf[rg * 4 + r][k];
#pragma unroll
        for (int r = 0; r < 4; ++r)
#pragma unroll
            for (int kk = 0; kk < 4; ++kk) {
#pragma unroll
                for (int c = 0; c < 4; ++c) acc[r][c] += rv[r][kk] * wv[kk][c];
            }
    }
#pragma unroll
    for (int r = 0; r < 4; ++r) {
        int gr = row0 + rg * 4 + r;
        v4 o = {acc[r][0], acc[r][1], acc[r][2], acc[r][3]};
        if (BIAS) {
#pragma unroll
            for (int c = 0; c < 4; ++c) o[c] += bias[cg * 4 + c];
        }
        if (gr < nn) *(v4*)&out[(size_t)gr * 128 + cg * 4] = o;
    }
    if (ALPHAS) {
        int head = cg >> 3;
#pragma unroll
        for (int r = 0; r < 4; ++r) {
            int gr = row0 + rg * 4 + r;
            float ps = 0.f, pd = 0.f;
#pragma unroll
            for (int c = 0; c < 4; ++c) {
                float hv = acc[r][c];
                ps += hv * avec_src[cg * 4 + c];
                pd += hv * avec_dst[cg * 4 + c];
            }
            ps += __shfl_xor(ps, 1); ps += __shfl_xor(ps, 2); ps += __shfl_xor(ps, 4);
            pd += __shfl_xor(pd, 1); pd += __shfl_xor(pd, 2); pd += __shfl_xor(pd, 4);
            if ((cg & 7) == 0 && gr < nn) {
                asrc[gr * 4 + head] = ps;
                adst[gr * 4 + head] = pd;
            }
        }
    }
}

// per-edge: alpha = lrelu(asrc[src]+adst[dst]+alpha_e), store + atomicMax m
__global__ __launch_bounds__(256) void k_edge_alpha(
    const float* __restrict__ edge_attr, const int* __restrict__ ei,
    const float* __restrict__ asrc, const float* __restrict__ adst,
    const float* __restrict__ edge_w, const float* __restrict__ a_edge,
    float* __restrict__ alpha, unsigned* __restrict__ m_enc, int E_) {
    __shared__ float aew[16];  // [k*4 + h]
    int tid = threadIdx.x;
    if (tid < 16) {
        int k = tid >> 2, hh = tid & 3;
        float s = 0.f;
        for (int c = 0; c < 32; ++c) s += edge_w[k * 128 + hh * 32 + c] * a_edge[hh * 32 + c];
        aew[tid] = s;
    }
    __syncthreads();
    int e = blockIdx.x * 256 + tid;
    if (e >= E_) return;
    int src = ei[e], dst = ei[E_ + e];
    v4 ea = *(const v4*)&edge_attr[(size_t)e * 4];
    v4 outv;
#pragma unroll
    for (int hh = 0; hh < 4; ++hh) {
        float a = asrc[src * 4 + hh] + adst[dst * 4 + hh] + ea[0] * aew[hh] +
                  ea[1] * aew[4 + hh] + ea[2] * aew[8 + hh] + ea[3] * aew[12 + hh];
        a = a > 0.f ? a : 0.2f * a;
        outv[hh] = a;
        atomicMax(&m_enc[dst * 4 + hh], encf(a));
    }
    *(v4*)&alpha[(size_t)e * 4] = outv;
}

__global__ __launch_bounds__(256) void k_mfix(unsigned* __restrict__ m, int n4) {
    int idx = blockIdx.x * 256 + threadIdx.x;
    if (idx >= n4) return;
    unsigned e = m[idx];
    float v = (e == 0u) ? 0.f : decf(e);
    ((float*)m)[idx] = v;
}

// wave per edge: ex = exp(alpha - m[dst]); denom += ex; out_acc[dst] += ex*hl[src]
__global__ __launch_bounds__(256) void k_edge_msg(
    const float* __restrict__ hl, const int* __restrict__ ei,
    const float* __restrict__ alpha, const float* __restrict__ mfl,
    float* __restrict__ denom, float* __restrict__ out_acc, int E_) {
    int e = blockIdx.x * 4 + (threadIdx.x >> 6);
    if (e >= E_) return;
    int lane = threadIdx.x & 63;
    int src = ei[e], dst = ei[E_ + e];
    int hh = lane >> 4;
    float ex = __expf(alpha[(size_t)e * 4 + hh] - mfl[dst * 4 + hh]);
    if ((lane & 15) == 0) atomicAdd(&denom[dst * 4 + hh], ex);
    float2 hv = ((const float2*)hl)[(size_t)src * 64 + lane];
    atomicAdd(&out_acc[(size_t)dst * 128 + lane * 2], ex * hv.x);
    atomicAdd(&out_acc[(size_t)dst * 128 + lane * 2 + 1], ex * hv.y);
}

// wave per node: normalize, +bias, +res, LN, relu -> h
__global__ __launch_bounds__(256) void k_node_fin(
    const float* __restrict__ out_acc, const float* __restrict__ denom,
    const float* __restrict__ bias, const float* __restrict__ lng,
    const float* __restrict__ lnb, float* __restrict__ h, int n) {
    int node = blockIdx.x * 4 + (threadIdx.x >> 6);
    if (node >= n) return;
    int lane = threadIdx.x & 63;
    int c0 = lane * 2;
    float d0 = denom[node * 4 + (lane >> 4)] + 1e-16f;
    float2 res = ((const float2*)h)[(size_t)node * 64 + lane];
    float2 oa = ((const float2*)out_acc)[(size_t)node * 64 + lane];
    float v0 = oa.x / d0 + bias[c0] + res.x;
    float v1 = oa.y / d0 + bias[c0 + 1] + res.y;
    float s = v0 + v1, sq = v0 * v0 + v1 * v1;
#pragma unroll
    for (int o = 32; o; o >>= 1) { s += __shfl_xor(s, o); sq += __shfl_xor(sq, o); }
    float mu = s * (1.f / 128.f);
    float var = sq * (1.f / 128.f) - mu * mu;
    float rs = rsqrtf(var + 1e-5f);
    float y0 = (v0 - mu) * rs * lng[c0] + lnb[c0];
    float y1 = (v1 - mu) * rs * lng[c0 + 1] + lnb[c0 + 1];
    float2 o2 = {fmaxf(y0, 0.f), fmaxf(y1, 0.f)};
    ((float2*)h)[(size_t)node * 64 + lane] = o2;
}

__device__ __forceinline__ int lower_bound_i(const int* a, int n, int key) {
    int lo = 0, hi = n;
    while (lo < hi) {
        int mid = (lo + hi) >> 1;
        if (a[mid] < key) lo = mid + 1; else hi = mid;
    }
    return lo;
}

// block per graph: mean+max pool over [start,end) -> comb[g][0:256)
__global__ __launch_bounds__(256) void k_pool(const float* __restrict__ h,
                                              const int* __restrict__ batch,
                                              float* __restrict__ comb, int n) {
    int g = blockIdx.x;
    int start = lower_bound_i(batch, n, g);
    int end = lower_bound_i(batch, n, g + 1);
    int tid = threadIdx.x, j = tid & 127, half = tid >> 7;
    __shared__ float ssum[2][128];
    __shared__ float smax[2][128];
    float s = 0.f, mx = -1e30f;
    for (int node = start + half; node < end; node += 2) {
        float v = h[(size_t)node * 128 + j];
        s += v;
        mx = fmaxf(mx, v);
    }
    ssum[half][j] = s;
    smax[half][j] = mx;
    __syncthreads();
    if (tid < 128) {
        float cnt = (float)(end - start);
        comb[g * 384 + j] = (ssum[0][j] + ssum[1][j]) / cnt;
        comb[g * 384 + 128 + j] = fmaxf(smax[0][j], smax[1][j]);
    }
}

__global__ __launch_bounds__(128) void k_had(const float* __restrict__ hf,
                                             const float* __restrict__ w1,
                                             const float* __restrict__ b1,
                                             const float* __restrict__ w2,
                                             const float* __restrict__ b2,
                                             float* __restrict__ comb) {
    __shared__ float h1[128];
    int g = blockIdx.x, j = threadIdx.x;
    float acc = b1[j];
#pragma unroll
    for (int k = 0; k < 12; ++k) acc += hf[g * 12 + k] * w1[k * 128 + j];
    h1[j] = fmaxf(acc, 0.f);
    __syncthreads();
    float a2 = b2[j];
    for (int k = 0; k < 128; ++k) a2 += h1[k] * w2[k * 128 + j];
    comb[g * 384 + 256 + j] = a2;
}

__global__ __launch_bounds__(128) void k_head(const float* __restrict__ comb,
                                              const float* __restrict__ w1,
                                              const float* __restrict__ b1,
                                              const float* __restrict__ w2,
                                              const float* __restrict__ b2,
                                              const float* __restrict__ w3,
                                              const float* __restrict__ b3,
                                              float* __restrict__ outp, int sigm) {
    __shared__ float cs[384];
    __shared__ float z1[128];
    __shared__ float z2[64];
    int g = blockIdx.x, j = threadIdx.x;
    for (int k = j; k < 384; k += 128) cs[k] = comb[g * 384 + k];
    __syncthreads();
    float acc = b1[j];
    for (int k = 0; k < 384; ++k) acc += cs[k] * w1[k * 128 + j];
    z1[j] = fmaxf(acc, 0.f);
    __syncthreads();
    if (j < 64) {
        float a2 = b2[j];
        for (int k = 0; k < 128; ++k) a2 += z1[k] * w2[k * 64 + j];
        z2[j] = fmaxf(a2, 0.f);
    }
    __syncthreads();
    if (j == 0) {
        float a3 = b3[0];
        for (int k = 0; k < 64; ++k) a3 += z2[k] * w3[k];
        if (sigm) a3 = 1.f / (1.f + __expf(-a3));
        outp[g] = a3;
    }
}

extern "C" void kernel_launch(void* const* d_in, const int* in_sizes, int n_in,
                              void* d_out, int out_size, void* d_ws, size_t ws_size,
                              hipStream_t stream) {
    const float* x = (const float*)d_in[0];
    const float* edge_attr = (const float*)d_in[1];
    const float* haddock = (const float*)d_in[2];
    const int* ei = (const int*)d_in[3];
    const int* batch = (const int*)d_in[4];
    const float* embed_w = (const float*)d_in[5];
    const float* embed_b = (const float*)d_in[6];
    const float* gat_lin_w = (const float*)d_in[7];
    const float* gat_att_src = (const float*)d_in[8];
    const float* gat_att_dst = (const float*)d_in[9];
    const float* gat_edge_w = (const float*)d_in[10];
    const float* gat_att_edge = (const float*)d_in[11];
    const float* gat_bias = (const float*)d_in[12];
    const float* ln_g = (const float*)d_in[13];
    const float* ln_b = (const float*)d_in[14];
    const float* had_w1 = (const float*)d_in[15];
    const float* had_b1 = (const float*)d_in[16];
    const float* had_w2 = (const float*)d_in[17];
    const float* had_b2 = (const float*)d_in[18];
    const float* int_w1 = (const float*)d_in[19];
    const float* int_b1 = (const float*)d_in[20];
    const float* int_w2 = (const float*)d_in[21];
    const float* int_b2 = (const float*)d_in[22];
    const float* int_w3 = (const float*)d_in[23];
    const float* int_b3 = (const float*)d_in[24];
    const float* aff_w1 = (const float*)d_in[25];
    const float* aff_b1 = (const float*)d_in[26];
    const float* aff_w2 = (const float*)d_in[27];
    const float* aff_b2 = (const float*)d_in[28];
    const float* aff_w3 = (const float*)d_in[29];
    const float* aff_b3 = (const float*)d_in[30];
    const float* mha_v_w = (const float*)d_in[31];
    const float* mha_v_b = (const float*)d_in[32];
    const float* mha_o_w = (const float*)d_in[33];
    const float* mha_o_b = (const float*)d_in[34];

    const int N_ = in_sizes[0] / 20;
    const int E_ = in_sizes[1] / 4;
    const int G_ = in_sizes[2] / 12;

    float* out_f = (float*)d_out;
    float* inter_out = out_f;
    float* aff_out = out_f + G_;
    float* attn_out = out_f + 2 * G_;
    float* h_buf = attn_out + (size_t)N_ * 128;
    float* hl = attn_out;  // scratch during GAT layers

    float* out_acc = (float*)d_ws;
    float* alphab = out_acc + (size_t)N_ * 128;
    float* asrc = alphab + (size_t)E_ * 4;
    float* adst = asrc + (size_t)N_ * 4;
    unsigned* m_enc = (unsigned*)(adst + (size_t)N_ * 4);
    float* denom = (float*)(m_enc + (size_t)N_ * 4);
    float* comb = denom + (size_t)N_ * 4;

    k_embed<<<(N_ * 128 + 255) / 256, 256, 0, stream>>>(x, embed_w, embed_b, h_buf, N_);

    for (int i = 0; i < 3; ++i) {
        k_zero<<<(N_ * 128 + 255) / 256, 256, 0, stream>>>(out_acc, denom, m_enc, N_);
        k_gemm128<true, false><<<(N_ + 31) / 32, 256, 0, stream>>>(
            h_buf, gat_lin_w + (size_t)i * 16384, nullptr, hl,
            gat_att_src + i * 128, gat_att_dst + i * 128, asrc, adst, N_);
        k_edge_alpha<<<(E_ + 255) / 256, 256, 0, stream>>>(
            edge_attr, ei, asrc, adst, gat_edge_w + (size_t)i * 512,
            gat_att_edge + i * 128, alphab, m_enc, E_);
        k_mfix<<<(N_ * 4 + 255) / 256, 256, 0, stream>>>(m_enc, N_ * 4);
        k_edge_msg<<<(E_ + 3) / 4, 256, 0, stream>>>(hl, ei, alphab, (const float*)m_enc,
                                                     denom, out_acc, E_);
        k_node_fin<<<(N_ + 3) / 4, 256, 0, stream>>>(out_acc, denom, gat_bias + i * 128,
                                                     ln_g + i * 128, ln_b + i * 128, h_buf, N_);
    }

    k_pool<<<G_, 256, 0, stream>>>(h_buf, batch, comb, N_);
    k_had<<<G_, 128, 0, stream>>>(haddock, had_w1, had_b1, had_w2, had_b2, comb);
    k_head<<<G_, 128, 0, stream>>>(comb, int_w1, int_b1, int_w2, int_b2, int_w3, int_b3,
                                   inter_out, 1);
    k_head<<<G_, 128, 0, stream>>>(comb, aff_w1, aff_b1, aff_w2, aff_b2, aff_w3, aff_b3,
                                   aff_out, 0);
    k_gemm128<false, true><<<(N_ + 31) / 32, 256, 0, stream>>>(
        h_buf, mha_v_w, mha_v_b, out_acc, nullptr, nullptr, nullptr, nullptr, N_);
    k_gemm128<false, true><<<(N_ + 31) / 32, 256, 0, stream>>>(
        out_acc, mha_o_w, mha_o_b, attn_out, nullptr, nullptr, nullptr, nullptr, N_);
}

// Round 2
// 722.228 us; speedup vs baseline: 3.2447x; 3.2447x over previous
//
#include <hip/hip_runtime.h>
#include <hip/hip_bf16.h>

typedef float v4 __attribute__((ext_vector_type(4)));

// h = relu(x @ embed_w + embed_b); x: [N,20], w: [20,128]
__global__ __launch_bounds__(256) void k_embed(const float* __restrict__ x,
                                               const float* __restrict__ w,
                                               const float* __restrict__ b,
                                               float* __restrict__ h, int n) {
    int idx = blockIdx.x * 256 + threadIdx.x;
    if (idx >= n * 128) return;
    int node = idx >> 7, j = idx & 127;
    float acc = b[j];
#pragma unroll
    for (int k = 0; k < 20; ++k) acc += x[node * 20 + k] * w[k * 128 + j];
    h[idx] = fmaxf(acc, 0.f);
}

// ---------------- CSR build (once; edge_index is layer-invariant) ----------------

__global__ __launch_bounds__(256) void k_csr_zero(int* __restrict__ cnt,
                                                  int* __restrict__ cursor, int n) {
    int i = blockIdx.x * 256 + threadIdx.x;
    if (i < n) { cnt[i] = 0; cursor[i] = 0; }
}

__global__ __launch_bounds__(256) void k_hist(const int* __restrict__ ei,
                                              int* __restrict__ cnt, int E_) {
    int e = blockIdx.x * 256 + threadIdx.x;
    if (e < E_) atomicAdd(&cnt[ei[E_ + e]], 1);
}

__global__ __launch_bounds__(256) void k_scan_local(const int* __restrict__ cnt,
                                                    int* __restrict__ ptr,
                                                    int* __restrict__ bsum, int n) {
    __shared__ int s[256];
    int t = threadIdx.x, i = blockIdx.x * 256 + t;
    int v = (i < n) ? cnt[i] : 0;
    s[t] = v;
    __syncthreads();
    for (int o = 1; o < 256; o <<= 1) {
        int x = (t >= o) ? s[t - o] : 0;
        __syncthreads();
        s[t] += x;
        __syncthreads();
    }
    if (i < n) ptr[i] = s[t] - v;  // exclusive within block
    if (t == 255) bsum[blockIdx.x] = s[255];
}

__global__ __launch_bounds__(256) void k_scan_bsum(int* __restrict__ bsum, int nb) {
    __shared__ int s[256];
    int t = threadIdx.x;
    int v = (t < nb) ? bsum[t] : 0;
    s[t] = v;
    __syncthreads();
    for (int o = 1; o < 256; o <<= 1) {
        int x = (t >= o) ? s[t - o] : 0;
        __syncthreads();
        s[t] += x;
        __syncthreads();
    }
    if (t < nb) bsum[t] = s[t] - v;  // exclusive
}

__global__ __launch_bounds__(256) void k_scan_add(int* __restrict__ ptr,
                                                  const int* __restrict__ bsum,
                                                  int n, int E_) {
    int i = blockIdx.x * 256 + threadIdx.x;
    if (i < n) ptr[i] += bsum[i >> 8];
    if (i == 0) ptr[n] = E_;
}

// pos[e] = sorted slot of edge e; esrc_s[pos] = src(e)
__global__ __launch_bounds__(256) void k_scatter(const int* __restrict__ ei,
                                                 const int* __restrict__ ptr,
                                                 int* __restrict__ cursor,
                                                 int* __restrict__ pos,
                                                 int* __restrict__ esrc_s, int E_) {
    int e = blockIdx.x * 256 + threadIdx.x;
    if (e >= E_) return;
    int d = ei[E_ + e];
    int p = ptr[d] + atomicAdd(&cursor[d], 1);
    pos[e] = p;
    esrc_s[p] = ei[e];
}

// ---------------- GEMM [nn,128] x [128,128] ----------------

template <bool ALPHAS, bool BIAS>
__global__ __launch_bounds__(256) void k_gemm128(
    const float* __restrict__ in, const float* __restrict__ W,
    const float* __restrict__ bias, float* __restrict__ out,
    const float* __restrict__ avec_src, const float* __restrict__ avec_dst,
    float* __restrict__ asrc, float* __restrict__ adst, int nn) {
    __shared__ float Ws[128 * 128];
    __shared__ float rowbuf[32][128];
    int tid = threadIdx.x;
    const v4* W4 = (const v4*)W;
    v4* Ws4 = (v4*)Ws;
    for (int i = tid; i < 4096; i += 256) Ws4[i] = W4[i];
    int row0 = blockIdx.x * 32;
    for (int i = tid; i < 1024; i += 256) {
        int r = i >> 5, c4 = i & 31;
        int gr = row0 + r;
        v4 v = {0.f, 0.f, 0.f, 0.f};
        if (gr < nn) v = ((const v4*)in)[(size_t)gr * 32 + c4];
        ((v4*)&rowbuf[r][0])[c4] = v;
    }
    __syncthreads();
    int rg = tid >> 5;   // rows rg*4..rg*4+3
    int cg = tid & 31;   // cols cg*4..cg*4+3
    float acc[4][4] = {};
    for (int k = 0; k < 128; k += 4) {
        v4 wv[4], rv[4];
#pragma unroll
        for (int kk = 0; kk < 4; ++kk) wv[kk] = *(const v4*)&Ws[(k + kk) * 128 + cg * 4];
#pragma unroll
        for (int r = 0; r < 4; ++r) rv[r] = *(const v4*)&rowbuf[rg * 4 + r][k];
#pragma unroll
        for (int r = 0; r < 4; ++r)
#pragma unroll
            for (int kk = 0; kk < 4; ++kk) {
#pragma unroll
                for (int c = 0; c < 4; ++c) acc[r][c] += rv[r][kk] * wv[kk][c];
            }
    }
#pragma unroll
    for (int r = 0; r < 4; ++r) {
        int gr = row0 + rg * 4 + r;
        v4 o = {acc[r][0], acc[r][1], acc[r][2], acc[r][3]};
        if (BIAS) {
#pragma unroll
            for (int c = 0; c < 4; ++c) o[c] += bias[cg * 4 + c];
        }
        if (gr < nn) *(v4*)&out[(size_t)gr * 128 + cg * 4] = o;
    }
    if (ALPHAS) {
        int head = cg >> 3;
#pragma unroll
        for (int r = 0; r < 4; ++r) {
            int gr = row0 + rg * 4 + r;
            float ps = 0.f, pd = 0.f;
#pragma unroll
            for (int c = 0; c < 4; ++c) {
                float hv = acc[r][c];
                ps += hv * avec_src[cg * 4 + c];
                pd += hv * avec_dst[cg * 4 + c];
            }
            ps += __shfl_xor(ps, 1); ps += __shfl_xor(ps, 2); ps += __shfl_xor(ps, 4);
            pd += __shfl_xor(pd, 1); pd += __shfl_xor(pd, 2); pd += __shfl_xor(pd, 4);
            if ((cg & 7) == 0 && gr < nn) {
                asrc[gr * 4 + head] = ps;
                adst[gr * 4 + head] = pd;
            }
        }
    }
}

// per-edge: alpha = lrelu(asrc[src]+adst[dst]+alpha_e) -> alpha_s[pos[e]]
__global__ __launch_bounds__(256) void k_edge_alpha(
    const float* __restrict__ edge_attr, const int* __restrict__ ei,
    const int* __restrict__ pos,
    const float* __restrict__ asrc, const float* __restrict__ adst,
    const float* __restrict__ edge_w, const float* __restrict__ a_edge,
    float* __restrict__ alpha_s, int E_) {
    __shared__ float aew[16];  // [k*4 + h]
    int tid = threadIdx.x;
    if (tid < 16) {
        int k = tid >> 2, hh = tid & 3;
        float s = 0.f;
        for (int c = 0; c < 32; ++c) s += edge_w[k * 128 + hh * 32 + c] * a_edge[hh * 32 + c];
        aew[tid] = s;
    }
    __syncthreads();
    int e = blockIdx.x * 256 + tid;
    if (e >= E_) return;
    int src = ei[e], dst = ei[E_ + e];
    v4 ea = *(const v4*)&edge_attr[(size_t)e * 4];
    v4 as = *(const v4*)&asrc[(size_t)src * 4];
    v4 ad = *(const v4*)&adst[(size_t)dst * 4];
    v4 outv;
#pragma unroll
    for (int hh = 0; hh < 4; ++hh) {
        float a = as[hh] + ad[hh] + ea[0] * aew[hh] + ea[1] * aew[4 + hh] +
                  ea[2] * aew[8 + hh] + ea[3] * aew[12 + hh];
        outv[hh] = a > 0.f ? a : 0.2f * a;
    }
    *(v4*)&alpha_s[(size_t)pos[e] * 4] = outv;
}

// wave per node: segment softmax + weighted aggregation + bias/res/LN/relu, no atomics
__global__ __launch_bounds__(256) void k_node_agg(
    const float* __restrict__ hl, const int* __restrict__ ptr,
    const int* __restrict__ esrc_s, const float* __restrict__ alpha_s,
    const float* __restrict__ bias, const float* __restrict__ lng,
    const float* __restrict__ lnb, float* __restrict__ h, int n) {
    int node = blockIdx.x * 4 + (threadIdx.x >> 6);
    if (node >= n) return;
    int lane = threadIdx.x & 63;
    int hh = lane >> 4;      // head for this lane's channel pair
    int c0 = lane * 2;
    int start = ptr[node], end = ptr[node + 1];

    // pass 1: per-head max (16 lanes of the head group split the edges)
    float m = -1e30f;
    for (int p = start + (lane & 15); p < end; p += 16)
        m = fmaxf(m, alpha_s[(size_t)p * 4 + hh]);
#pragma unroll
    for (int o = 1; o < 16; o <<= 1) m = fmaxf(m, __shfl_xor(m, o));

    // pass 2: serial over edges, accumulate exp-weighted messages
    float acc0 = 0.f, acc1 = 0.f, den = 0.f;
    int p = start;
    int srcp = (p < end) ? esrc_s[p] : 0;
    for (; p < end; ++p) {
        int srcn = (p + 1 < end) ? esrc_s[p + 1] : 0;
        float a = alpha_s[(size_t)p * 4 + hh];
        float ex = __expf(a - m);
        float2 hv = ((const float2*)hl)[(size_t)srcp * 64 + lane];
        acc0 += ex * hv.x;
        acc1 += ex * hv.y;
        den += ex;
        srcp = srcn;
    }

    float inv = 1.f / (den + 1e-16f);
    float2 res = ((const float2*)h)[(size_t)node * 64 + lane];
    float v0 = acc0 * inv + bias[c0] + res.x;
    float v1 = acc1 * inv + bias[c0 + 1] + res.y;
    float s = v0 + v1, sq = v0 * v0 + v1 * v1;
#pragma unroll
    for (int o = 32; o; o >>= 1) { s += __shfl_xor(s, o); sq += __shfl_xor(sq, o); }
    float mu = s * (1.f / 128.f);
    float var = sq * (1.f / 128.f) - mu * mu;
    float rs = rsqrtf(var + 1e-5f);
    float y0 = (v0 - mu) * rs * lng[c0] + lnb[c0];
    float y1 = (v1 - mu) * rs * lng[c0 + 1] + lnb[c0 + 1];
    float2 o2 = {fmaxf(y0, 0.f), fmaxf(y1, 0.f)};
    ((float2*)h)[(size_t)node * 64 + lane] = o2;
}

__device__ __forceinline__ int lower_bound_i(const int* a, int n, int key) {
    int lo = 0, hi = n;
    while (lo < hi) {
        int mid = (lo + hi) >> 1;
        if (a[mid] < key) lo = mid + 1; else hi = mid;
    }
    return lo;
}

// block per graph: mean+max pool over [start,end) -> comb[g][0:256)
__global__ __launch_bounds__(256) void k_pool(const float* __restrict__ h,
                                              const int* __restrict__ batch,
                                              float* __restrict__ comb, int n) {
    int g = blockIdx.x;
    int start = lower_bound_i(batch, n, g);
    int end = lower_bound_i(batch, n, g + 1);
    int tid = threadIdx.x, j = tid & 127, half = tid >> 7;
    __shared__ float ssum[2][128];
    __shared__ float smax[2][128];
    float s = 0.f, mx = -1e30f;
    for (int node = start + half; node < end; node += 2) {
        float v = h[(size_t)node * 128 + j];
        s += v;
        mx = fmaxf(mx, v);
    }
    ssum[half][j] = s;
    smax[half][j] = mx;
    __syncthreads();
    if (tid < 128) {
        float cnt = (float)(end - start);
        comb[g * 384 + j] = (ssum[0][j] + ssum[1][j]) / cnt;
        comb[g * 384 + 128 + j] = fmaxf(smax[0][j], smax[1][j]);
    }
}

__global__ __launch_bounds__(128) void k_had(const float* __restrict__ hf,
                                             const float* __restrict__ w1,
                                             const float* __restrict__ b1,
                                             const float* __restrict__ w2,
                                             const float* __restrict__ b2,
                                             float* __restrict__ comb) {
    __shared__ float h1[128];
    int g = blockIdx.x, j = threadIdx.x;
    float acc = b1[j];
#pragma unroll
    for (int k = 0; k < 12; ++k) acc += hf[g * 12 + k] * w1[k * 128 + j];
    h1[j] = fmaxf(acc, 0.f);
    __syncthreads();
    float a2 = b2[j];
    for (int k = 0; k < 128; ++k) a2 += h1[k] * w2[k * 128 + j];
    comb[g * 384 + 256 + j] = a2;
}

__global__ __launch_bounds__(128) void k_head(const float* __restrict__ comb,
                                              const float* __restrict__ w1,
                                              const float* __restrict__ b1,
                                              const float* __restrict__ w2,
                                              const float* __restrict__ b2,
                                              const float* __restrict__ w3,
                                              const float* __restrict__ b3,
                                              float* __restrict__ outp, int sigm) {
    __shared__ float cs[384];
    __shared__ float z1[128];
    __shared__ float z2[64];
    int g = blockIdx.x, j = threadIdx.x;
    for (int k = j; k < 384; k += 128) cs[k] = comb[g * 384 + k];
    __syncthreads();
    float acc = b1[j];
    for (int k = 0; k < 384; ++k) acc += cs[k] * w1[k * 128 + j];
    z1[j] = fmaxf(acc, 0.f);
    __syncthreads();
    if (j < 64) {
        float a2 = b2[j];
        for (int k = 0; k < 128; ++k) a2 += z1[k] * w2[k * 64 + j];
        z2[j] = fmaxf(a2, 0.f);
    }
    __syncthreads();
    if (j == 0) {
        float a3 = b3[0];
        for (int k = 0; k < 64; ++k) a3 += z2[k] * w3[k];
        if (sigm) a3 = 1.f / (1.f + __expf(-a3));
        outp[g] = a3;
    }
}

extern "C" void kernel_launch(void* const* d_in, const int* in_sizes, int n_in,
                              void* d_out, int out_size, void* d_ws, size_t ws_size,
                              hipStream_t stream) {
    const float* x = (const float*)d_in[0];
    const float* edge_attr = (const float*)d_in[1];
    const float* haddock = (const float*)d_in[2];
    const int* ei = (const int*)d_in[3];
    const int* batch = (const int*)d_in[4];
    const float* embed_w = (const float*)d_in[5];
    const float* embed_b = (const float*)d_in[6];
    const float* gat_lin_w = (const float*)d_in[7];
    const float* gat_att_src = (const float*)d_in[8];
    const float* gat_att_dst = (const float*)d_in[9];
    const float* gat_edge_w = (const float*)d_in[10];
    const float* gat_att_edge = (const float*)d_in[11];
    const float* gat_bias = (const float*)d_in[12];
    const float* ln_g = (const float*)d_in[13];
    const float* ln_b = (const float*)d_in[14];
    const float* had_w1 = (const float*)d_in[15];
    const float* had_b1 = (const float*)d_in[16];
    const float* had_w2 = (const float*)d_in[17];
    const float* had_b2 = (const float*)d_in[18];
    const float* int_w1 = (const float*)d_in[19];
    const float* int_b1 = (const float*)d_in[20];
    const float* int_w2 = (const float*)d_in[21];
    const float* int_b2 = (const float*)d_in[22];
    const float* int_w3 = (const float*)d_in[23];
    const float* int_b3 = (const float*)d_in[24];
    const float* aff_w1 = (const float*)d_in[25];
    const float* aff_b1 = (const float*)d_in[26];
    const float* aff_w2 = (const float*)d_in[27];
    const float* aff_b2 = (const float*)d_in[28];
    const float* aff_w3 = (const float*)d_in[29];
    const float* aff_b3 = (const float*)d_in[30];
    const float* mha_v_w = (const float*)d_in[31];
    const float* mha_v_b = (const float*)d_in[32];
    const float* mha_o_w = (const float*)d_in[33];
    const float* mha_o_b = (const float*)d_in[34];

    const int N_ = in_sizes[0] / 20;
    const int E_ = in_sizes[1] / 4;
    const int G_ = in_sizes[2] / 12;

    float* out_f = (float*)d_out;
    float* inter_out = out_f;
    float* aff_out = out_f + G_;
    float* attn_out = out_f + 2 * G_;
    float* h_buf = attn_out + (size_t)N_ * 128;
    float* hl = attn_out;  // scratch during GAT layers

    // workspace layout
    int* cnt = (int*)d_ws;
    int* cursor = cnt + N_;
    int* ptr = cursor + N_;              // N_+1
    int* bsum = ptr + N_ + 1;            // 256
    int* pos = bsum + 256;               // E_
    int* esrc_s = pos + E_;              // E_
    float* alpha_s = (float*)(esrc_s + E_);   // E_*4
    float* asrc = alpha_s + (size_t)E_ * 4;   // N_*4
    float* adst = asrc + (size_t)N_ * 4;      // N_*4
    float* comb = adst + (size_t)N_ * 4;      // G_*384
    float* mha_tmp = comb + (size_t)G_ * 384; // N_*128

    const int nb_scan = (N_ + 255) / 256;

    k_embed<<<(N_ * 128 + 255) / 256, 256, 0, stream>>>(x, embed_w, embed_b, h_buf, N_);

    // CSR build (once)
    k_csr_zero<<<nb_scan, 256, 0, stream>>>(cnt, cursor, N_);
    k_hist<<<(E_ + 255) / 256, 256, 0, stream>>>(ei, cnt, E_);
    k_scan_local<<<nb_scan, 256, 0, stream>>>(cnt, ptr, bsum, N_);
    k_scan_bsum<<<1, 256, 0, stream>>>(bsum, nb_scan);
    k_scan_add<<<nb_scan, 256, 0, stream>>>(ptr, bsum, N_, E_);
    k_scatter<<<(E_ + 255) / 256, 256, 0, stream>>>(ei, ptr, cursor, pos, esrc_s, E_);

    for (int i = 0; i < 3; ++i) {
        k_gemm128<true, false><<<(N_ + 31) / 32, 256, 0, stream>>>(
            h_buf, gat_lin_w + (size_t)i * 16384, nullptr, hl,
            gat_att_src + i * 128, gat_att_dst + i * 128, asrc, adst, N_);
        k_edge_alpha<<<(E_ + 255) / 256, 256, 0, stream>>>(
            edge_attr, ei, pos, asrc, adst, gat_edge_w + (size_t)i * 512,
            gat_att_edge + i * 128, alpha_s, E_);
        k_node_agg<<<(N_ + 3) / 4, 256, 0, stream>>>(
            hl, ptr, esrc_s, alpha_s, gat_bias + i * 128,
            ln_g + i * 128, ln_b + i * 128, h_buf, N_);
    }

    k_pool<<<G_, 256, 0, stream>>>(h_buf, batch, comb, N_);
    k_had<<<G_, 128, 0, stream>>>(haddock, had_w1, had_b1, had_w2, had_b2, comb);
    k_head<<<G_, 128, 0, stream>>>(comb, int_w1, int_b1, int_w2, int_b2, int_w3, int_b3,
                                   inter_out, 1);
    k_head<<<G_, 128, 0, stream>>>(comb, aff_w1, aff_b1, aff_w2, aff_b2, aff_w3, aff_b3,
                                   aff_out, 0);
    k_gemm128<false, true><<<(N_ + 31) / 32, 256, 0, stream>>>(
        h_buf, mha_v_w, mha_v_b, mha_tmp, nullptr, nullptr, nullptr, nullptr, N_);
    k_gemm128<false, true><<<(N_ + 31) / 32, 256, 0, stream>>>(
        mha_tmp, mha_o_w, mha_o_b, attn_out, nullptr, nullptr, nullptr, nullptr, N_);
}

// Round 3
// 606.750 us; speedup vs baseline: 3.8623x; 1.1903x over previous
//
#include <hip/hip_runtime.h>
#include <hip/hip_bf16.h>

typedef float v4 __attribute__((ext_vector_type(4)));

// h = relu(x @ embed_w + embed_b); x: [N,20], w: [20,128]
__global__ __launch_bounds__(256) void k_embed(const float* __restrict__ x,
                                               const float* __restrict__ w,
                                               const float* __restrict__ b,
                                               float* __restrict__ h, int n) {
    int idx = blockIdx.x * 256 + threadIdx.x;
    if (idx >= n * 128) return;
    int node = idx >> 7, j = idx & 127;
    float acc = b[j];
#pragma unroll
    for (int k = 0; k < 20; ++k) acc += x[node * 20 + k] * w[k * 128 + j];
    h[idx] = fmaxf(acc, 0.f);
}

// ---------------- CSR build (once; edge_index is layer-invariant) ----------------

__global__ __launch_bounds__(256) void k_csr_zero(int* __restrict__ cnt,
                                                  int* __restrict__ cursor, int n) {
    int i = blockIdx.x * 256 + threadIdx.x;
    if (i < n) { cnt[i] = 0; cursor[i] = 0; }
}

__global__ __launch_bounds__(256) void k_hist(const int* __restrict__ ei,
                                              int* __restrict__ cnt, int E_) {
    int e = blockIdx.x * 256 + threadIdx.x;
    if (e < E_) atomicAdd(&cnt[ei[E_ + e]], 1);
}

__global__ __launch_bounds__(256) void k_scan_local(const int* __restrict__ cnt,
                                                    int* __restrict__ ptr,
                                                    int* __restrict__ bsum, int n) {
    __shared__ int s[256];
    int t = threadIdx.x, i = blockIdx.x * 256 + t;
    int v = (i < n) ? cnt[i] : 0;
    s[t] = v;
    __syncthreads();
    for (int o = 1; o < 256; o <<= 1) {
        int x = (t >= o) ? s[t - o] : 0;
        __syncthreads();
        s[t] += x;
        __syncthreads();
    }
    if (i < n) ptr[i] = s[t] - v;  // exclusive within block
    if (t == 255) bsum[blockIdx.x] = s[255];
}

__global__ __launch_bounds__(256) void k_scan_bsum(int* __restrict__ bsum, int nb) {
    __shared__ int s[256];
    int t = threadIdx.x;
    int v = (t < nb) ? bsum[t] : 0;
    s[t] = v;
    __syncthreads();
    for (int o = 1; o < 256; o <<= 1) {
        int x = (t >= o) ? s[t - o] : 0;
        __syncthreads();
        s[t] += x;
        __syncthreads();
    }
    if (t < nb) bsum[t] = s[t] - v;  // exclusive
}

__global__ __launch_bounds__(256) void k_scan_add(int* __restrict__ ptr,
                                                  const int* __restrict__ bsum,
                                                  int n, int E_) {
    int i = blockIdx.x * 256 + threadIdx.x;
    if (i < n) ptr[i] += bsum[i >> 8];
    if (i == 0) ptr[n] = E_;
}

// pos[e] = sorted slot of edge e; esrc_s[pos] = src(e)
__global__ __launch_bounds__(256) void k_scatter(const int* __restrict__ ei,
                                                 const int* __restrict__ ptr,
                                                 int* __restrict__ cursor,
                                                 int* __restrict__ pos,
                                                 int* __restrict__ esrc_s, int E_) {
    int e = blockIdx.x * 256 + threadIdx.x;
    if (e >= E_) return;
    int d = ei[E_ + e];
    int p = ptr[d] + atomicAdd(&cursor[d], 1);
    pos[e] = p;
    esrc_s[p] = ei[e];
}

// ---------------- GEMM [nn,128] x [128,128] ----------------

template <bool ALPHAS, bool BIAS>
__global__ __launch_bounds__(256) void k_gemm128(
    const float* __restrict__ in, const float* __restrict__ W,
    const float* __restrict__ bias, float* __restrict__ out,
    const float* __restrict__ avec_src, const float* __restrict__ avec_dst,
    float* __restrict__ asrc, float* __restrict__ adst, int nn) {
    __shared__ float Ws[128 * 128];
    __shared__ float rowbuf[32][128];
    int tid = threadIdx.x;
    const v4* W4 = (const v4*)W;
    v4* Ws4 = (v4*)Ws;
    for (int i = tid; i < 4096; i += 256) Ws4[i] = W4[i];
    int row0 = blockIdx.x * 32;
    for (int i = tid; i < 1024; i += 256) {
        int r = i >> 5, c4 = i & 31;
        int gr = row0 + r;
        v4 v = {0.f, 0.f, 0.f, 0.f};
        if (gr < nn) v = ((const v4*)in)[(size_t)gr * 32 + c4];
        ((v4*)&rowbuf[r][0])[c4] = v;
    }
    __syncthreads();
    int rg = tid >> 5;   // rows rg*4..rg*4+3
    int cg = tid & 31;   // cols cg*4..cg*4+3
    float acc[4][4] = {};
    for (int k = 0; k < 128; k += 4) {
        v4 wv[4], rv[4];
#pragma unroll
        for (int kk = 0; kk < 4; ++kk) wv[kk] = *(const v4*)&Ws[(k + kk) * 128 + cg * 4];
#pragma unroll
        for (int r = 0; r < 4; ++r) rv[r] = *(const v4*)&rowbuf[rg * 4 + r][k];
#pragma unroll
        for (int r = 0; r < 4; ++r)
#pragma unroll
            for (int kk = 0; kk < 4; ++kk) {
#pragma unroll
                for (int c = 0; c < 4; ++c) acc[r][c] += rv[r][kk] * wv[kk][c];
            }
    }
#pragma unroll
    for (int r = 0; r < 4; ++r) {
        int gr = row0 + rg * 4 + r;
        v4 o = {acc[r][0], acc[r][1], acc[r][2], acc[r][3]};
        if (BIAS) {
#pragma unroll
            for (int c = 0; c < 4; ++c) o[c] += bias[cg * 4 + c];
        }
        if (gr < nn) *(v4*)&out[(size_t)gr * 128 + cg * 4] = o;
    }
    if (ALPHAS) {
        int head = cg >> 3;
#pragma unroll
        for (int r = 0; r < 4; ++r) {
            int gr = row0 + rg * 4 + r;
            float ps = 0.f, pd = 0.f;
#pragma unroll
            for (int c = 0; c < 4; ++c) {
                float hv = acc[r][c];
                ps += hv * avec_src[cg * 4 + c];
                pd += hv * avec_dst[cg * 4 + c];
            }
            ps += __shfl_xor(ps, 1); ps += __shfl_xor(ps, 2); ps += __shfl_xor(ps, 4);
            pd += __shfl_xor(pd, 1); pd += __shfl_xor(pd, 2); pd += __shfl_xor(pd, 4);
            if ((cg & 7) == 0 && gr < nn) {
                asrc[gr * 4 + head] = ps;
                adst[gr * 4 + head] = pd;
            }
        }
    }
}

// Wc = Vw @ Ow ; bc = vb @ Ow + ob   (seq_len=1 MHA reduces to one affine map)
__global__ __launch_bounds__(128) void k_fuse_vo(const float* __restrict__ vw,
                                                 const float* __restrict__ vb,
                                                 const float* __restrict__ ow,
                                                 const float* __restrict__ ob,
                                                 float* __restrict__ Wc,
                                                 float* __restrict__ bc) {
    int k = blockIdx.x, j = threadIdx.x;
    float acc = 0.f;
    for (int m = 0; m < 128; ++m) acc += vw[k * 128 + m] * ow[m * 128 + j];
    Wc[k * 128 + j] = acc;
    if (k == 0) {
        float b = ob[j];
        for (int m = 0; m < 128; ++m) b += vb[m] * ow[m * 128 + j];
        bc[j] = b;
    }
}

// per-edge: alpha = lrelu(asrc[src]+adst[dst]+alpha_e) -> alpha_s[pos[e]]
__global__ __launch_bounds__(256) void k_edge_alpha(
    const float* __restrict__ edge_attr, const int* __restrict__ ei,
    const int* __restrict__ pos,
    const float* __restrict__ asrc, const float* __restrict__ adst,
    const float* __restrict__ edge_w, const float* __restrict__ a_edge,
    float* __restrict__ alpha_s, int E_) {
    __shared__ float aew[16];  // [k*4 + h]
    int tid = threadIdx.x;
    if (tid < 16) {
        int k = tid >> 2, hh = tid & 3;
        float s = 0.f;
        for (int c = 0; c < 32; ++c) s += edge_w[k * 128 + hh * 32 + c] * a_edge[hh * 32 + c];
        aew[tid] = s;
    }
    __syncthreads();
    int e = blockIdx.x * 256 + tid;
    if (e >= E_) return;
    int src = ei[e], dst = ei[E_ + e];
    v4 ea = *(const v4*)&edge_attr[(size_t)e * 4];
    v4 as = *(const v4*)&asrc[(size_t)src * 4];
    v4 ad = *(const v4*)&adst[(size_t)dst * 4];
    v4 outv;
#pragma unroll
    for (int hh = 0; hh < 4; ++hh) {
        float a = as[hh] + ad[hh] + ea[0] * aew[hh] + ea[1] * aew[4 + hh] +
                  ea[2] * aew[8 + hh] + ea[3] * aew[12 + hh];
        outv[hh] = a > 0.f ? a : 0.2f * a;
    }
    *(v4*)&alpha_s[(size_t)pos[e] * 4] = outv;
}

// wave per node: segment softmax + weighted aggregation + bias/res/LN/relu, no atomics
__global__ __launch_bounds__(256) void k_node_agg(
    const float* __restrict__ hl, const int* __restrict__ ptr,
    const int* __restrict__ esrc_s, const float* __restrict__ alpha_s,
    const float* __restrict__ bias, const float* __restrict__ lng,
    const float* __restrict__ lnb, float* __restrict__ h, int n) {
    int node = blockIdx.x * 4 + (threadIdx.x >> 6);
    if (node >= n) return;
    int lane = threadIdx.x & 63;
    int hh = lane >> 4;      // head for this lane's channel pair
    int c0 = lane * 2;
    int start = ptr[node], end = ptr[node + 1];

    // pass 1: per-head max (16 lanes of the head group split the edges)
    float m = -1e30f;
    for (int p = start + (lane & 15); p < end; p += 16)
        m = fmaxf(m, alpha_s[(size_t)p * 4 + hh]);
#pragma unroll
    for (int o = 1; o < 16; o <<= 1) m = fmaxf(m, __shfl_xor(m, o));

    // pass 2: serial over edges, accumulate exp-weighted messages
    float acc0 = 0.f, acc1 = 0.f, den = 0.f;
    int p = start;
    int srcp = (p < end) ? esrc_s[p] : 0;
    for (; p < end; ++p) {
        int srcn = (p + 1 < end) ? esrc_s[p + 1] : 0;
        float a = alpha_s[(size_t)p * 4 + hh];
        float ex = __expf(a - m);
        float2 hv = ((const float2*)hl)[(size_t)srcp * 64 + lane];
        acc0 += ex * hv.x;
        acc1 += ex * hv.y;
        den += ex;
        srcp = srcn;
    }

    float inv = 1.f / (den + 1e-16f);
    float2 res = ((const float2*)h)[(size_t)node * 64 + lane];
    float v0 = acc0 * inv + bias[c0] + res.x;
    float v1 = acc1 * inv + bias[c0 + 1] + res.y;
    float s = v0 + v1, sq = v0 * v0 + v1 * v1;
#pragma unroll
    for (int o = 32; o; o >>= 1) { s += __shfl_xor(s, o); sq += __shfl_xor(sq, o); }
    float mu = s * (1.f / 128.f);
    float var = sq * (1.f / 128.f) - mu * mu;
    float rs = rsqrtf(var + 1e-5f);
    float y0 = (v0 - mu) * rs * lng[c0] + lnb[c0];
    float y1 = (v1 - mu) * rs * lng[c0 + 1] + lnb[c0 + 1];
    float2 o2 = {fmaxf(y0, 0.f), fmaxf(y1, 0.f)};
    ((float2*)h)[(size_t)node * 64 + lane] = o2;
}

__device__ __forceinline__ int lower_bound_i(const int* a, int n, int key) {
    int lo = 0, hi = n;
    while (lo < hi) {
        int mid = (lo + hi) >> 1;
        if (a[mid] < key) lo = mid + 1; else hi = mid;
    }
    return lo;
}

// ---------------- two-stage pooling ----------------

__global__ __launch_bounds__(256) void k_pool_zero(float* __restrict__ gsum,
                                                   float* __restrict__ gmax, int g128) {
    int i = blockIdx.x * 256 + threadIdx.x;
    if (i < g128) { gsum[i] = 0.f; gmax[i] = 0.f; }
}

// 2048 blocks; each owns a contiguous node slice. batch sorted; h >= 0 (relu),
// so float atomicMax == int atomicMax on the bit pattern.
__global__ __launch_bounds__(256) void k_pool_part(const float* __restrict__ h,
                                                   const int* __restrict__ batch,
                                                   float* __restrict__ gsum,
                                                   float* __restrict__ gmax,
                                                   int n, int chunk) {
    int start = blockIdx.x * chunk;
    int end = min(start + chunk, n);
    if (start >= end) return;
    int j = threadIdx.x & 127, half = threadIdx.x >> 7;
    float s = 0.f, mx = 0.f;
    int curg = -1;
    for (int node = start + half; node < end; node += 2) {
        int g = batch[node];
        if (g != curg) {
            if (curg >= 0) {
                atomicAdd(&gsum[curg * 128 + j], s);
                atomicMax((int*)&gmax[curg * 128 + j], __float_as_int(mx));
            }
            curg = g; s = 0.f; mx = 0.f;
        }
        float v = h[(size_t)node * 128 + j];
        s += v;
        mx = fmaxf(mx, v);
    }
    if (curg >= 0) {
        atomicAdd(&gsum[curg * 128 + j], s);
        atomicMax((int*)&gmax[curg * 128 + j], __float_as_int(mx));
    }
}

__global__ __launch_bounds__(128) void k_pool_fin(const float* __restrict__ gsum,
                                                  const float* __restrict__ gmax,
                                                  const int* __restrict__ batch,
                                                  float* __restrict__ comb, int n) {
    int g = blockIdx.x, j = threadIdx.x;
    int start = lower_bound_i(batch, n, g);
    int end = lower_bound_i(batch, n, g + 1);
    float cnt = (float)(end - start);
    comb[g * 384 + j] = gsum[g * 128 + j] / cnt;
    comb[g * 384 + 128 + j] = gmax[g * 128 + j];
}

__global__ __launch_bounds__(128) void k_had(const float* __restrict__ hf,
                                             const float* __restrict__ w1,
                                             const float* __restrict__ b1,
                                             const float* __restrict__ w2,
                                             const float* __restrict__ b2,
                                             float* __restrict__ comb) {
    __shared__ float h1[128];
    int g = blockIdx.x, j = threadIdx.x;
    float acc = b1[j];
#pragma unroll
    for (int k = 0; k < 12; ++k) acc += hf[g * 12 + k] * w1[k * 128 + j];
    h1[j] = fmaxf(acc, 0.f);
    __syncthreads();
    float a2 = b2[j];
    for (int k = 0; k < 128; ++k) a2 += h1[k] * w2[k * 128 + j];
    comb[g * 384 + 256 + j] = a2;
}

__global__ __launch_bounds__(128) void k_head(const float* __restrict__ comb,
                                              const float* __restrict__ w1,
                                              const float* __restrict__ b1,
                                              const float* __restrict__ w2,
                                              const float* __restrict__ b2,
                                              const float* __restrict__ w3,
                                              const float* __restrict__ b3,
                                              float* __restrict__ outp, int sigm) {
    __shared__ float cs[384];
    __shared__ float z1[128];
    __shared__ float z2[64];
    int g = blockIdx.x, j = threadIdx.x;
    for (int k = j; k < 384; k += 128) cs[k] = comb[g * 384 + k];
    __syncthreads();
    float acc = b1[j];
    for (int k = 0; k < 384; ++k) acc += cs[k] * w1[k * 128 + j];
    z1[j] = fmaxf(acc, 0.f);
    __syncthreads();
    if (j < 64) {
        float a2 = b2[j];
        for (int k = 0; k < 128; ++k) a2 += z1[k] * w2[k * 64 + j];
        z2[j] = fmaxf(a2, 0.f);
    }
    __syncthreads();
    if (j == 0) {
        float a3 = b3[0];
        for (int k = 0; k < 64; ++k) a3 += z2[k] * w3[k];
        if (sigm) a3 = 1.f / (1.f + __expf(-a3));
        outp[g] = a3;
    }
}

extern "C" void kernel_launch(void* const* d_in, const int* in_sizes, int n_in,
                              void* d_out, int out_size, void* d_ws, size_t ws_size,
                              hipStream_t stream) {
    const float* x = (const float*)d_in[0];
    const float* edge_attr = (const float*)d_in[1];
    const float* haddock = (const float*)d_in[2];
    const int* ei = (const int*)d_in[3];
    const int* batch = (const int*)d_in[4];
    const float* embed_w = (const float*)d_in[5];
    const float* embed_b = (const float*)d_in[6];
    const float* gat_lin_w = (const float*)d_in[7];
    const float* gat_att_src = (const float*)d_in[8];
    const float* gat_att_dst = (const float*)d_in[9];
    const float* gat_edge_w = (const float*)d_in[10];
    const float* gat_att_edge = (const float*)d_in[11];
    const float* gat_bias = (const float*)d_in[12];
    const float* ln_g = (const float*)d_in[13];
    const float* ln_b = (const float*)d_in[14];
    const float* had_w1 = (const float*)d_in[15];
    const float* had_b1 = (const float*)d_in[16];
    const float* had_w2 = (const float*)d_in[17];
    const float* had_b2 = (const float*)d_in[18];
    const float* int_w1 = (const float*)d_in[19];
    const float* int_b1 = (const float*)d_in[20];
    const float* int_w2 = (const float*)d_in[21];
    const float* int_b2 = (const float*)d_in[22];
    const float* int_w3 = (const float*)d_in[23];
    const float* int_b3 = (const float*)d_in[24];
    const float* aff_w1 = (const float*)d_in[25];
    const float* aff_b1 = (const float*)d_in[26];
    const float* aff_w2 = (const float*)d_in[27];
    const float* aff_b2 = (const float*)d_in[28];
    const float* aff_w3 = (const float*)d_in[29];
    const float* aff_b3 = (const float*)d_in[30];
    const float* mha_v_w = (const float*)d_in[31];
    const float* mha_v_b = (const float*)d_in[32];
    const float* mha_o_w = (const float*)d_in[33];
    const float* mha_o_b = (const float*)d_in[34];

    const int N_ = in_sizes[0] / 20;
    const int E_ = in_sizes[1] / 4;
    const int G_ = in_sizes[2] / 12;

    float* out_f = (float*)d_out;
    float* inter_out = out_f;
    float* aff_out = out_f + G_;
    float* attn_out = out_f + 2 * G_;
    float* h_buf = attn_out + (size_t)N_ * 128;
    float* hl = attn_out;  // scratch during GAT layers

    // workspace layout
    int* cnt = (int*)d_ws;
    int* cursor = cnt + N_;
    int* ptr = cursor + N_;              // N_+1
    int* bsum = ptr + N_ + 1;            // 256
    int* pos = bsum + 256;               // E_
    int* esrc_s = pos + E_;              // E_
    float* alpha_s = (float*)(esrc_s + E_);   // E_*4
    float* asrc = alpha_s + (size_t)E_ * 4;   // N_*4
    float* adst = asrc + (size_t)N_ * 4;      // N_*4
    float* comb = adst + (size_t)N_ * 4;      // G_*384
    float* gsum = comb + (size_t)G_ * 384;    // G_*128
    float* gmax = gsum + (size_t)G_ * 128;    // G_*128
    float* Wc = gmax + (size_t)G_ * 128;      // 128*128
    float* bc = Wc + 128 * 128;               // 128

    const int nb_scan = (N_ + 255) / 256;
    const int POOL_BLOCKS = 2048;
    const int chunk = (N_ + POOL_BLOCKS - 1) / POOL_BLOCKS;

    k_embed<<<(N_ * 128 + 255) / 256, 256, 0, stream>>>(x, embed_w, embed_b, h_buf, N_);

    // CSR build (once)
    k_csr_zero<<<nb_scan, 256, 0, stream>>>(cnt, cursor, N_);
    k_hist<<<(E_ + 255) / 256, 256, 0, stream>>>(ei, cnt, E_);
    k_scan_local<<<nb_scan, 256, 0, stream>>>(cnt, ptr, bsum, N_);
    k_scan_bsum<<<1, 256, 0, stream>>>(bsum, nb_scan);
    k_scan_add<<<nb_scan, 256, 0, stream>>>(ptr, bsum, N_, E_);
    k_scatter<<<(E_ + 255) / 256, 256, 0, stream>>>(ei, ptr, cursor, pos, esrc_s, E_);

    // MHA algebraic fusion (independent of the layer loop)
    k_fuse_vo<<<128, 128, 0, stream>>>(mha_v_w, mha_v_b, mha_o_w, mha_o_b, Wc, bc);
    k_pool_zero<<<(G_ * 128 + 255) / 256, 256, 0, stream>>>(gsum, gmax, G_ * 128);

    for (int i = 0; i < 3; ++i) {
        k_gemm128<true, false><<<(N_ + 31) / 32, 256, 0, stream>>>(
            h_buf, gat_lin_w + (size_t)i * 16384, nullptr, hl,
            gat_att_src + i * 128, gat_att_dst + i * 128, asrc, adst, N_);
        k_edge_alpha<<<(E_ + 255) / 256, 256, 0, stream>>>(
            edge_attr, ei, pos, asrc, adst, gat_edge_w + (size_t)i * 512,
            gat_att_edge + i * 128, alpha_s, E_);
        k_node_agg<<<(N_ + 3) / 4, 256, 0, stream>>>(
            hl, ptr, esrc_s, alpha_s, gat_bias + i * 128,
            ln_g + i * 128, ln_b + i * 128, h_buf, N_);
    }

    k_pool_part<<<POOL_BLOCKS, 256, 0, stream>>>(h_buf, batch, gsum, gmax, N_, chunk);
    k_pool_fin<<<G_, 128, 0, stream>>>(gsum, gmax, batch, comb, N_);
    k_had<<<G_, 128, 0, stream>>>(haddock, had_w1, had_b1, had_w2, had_b2, comb);
    k_head<<<G_, 128, 0, stream>>>(comb, int_w1, int_b1, int_w2, int_b2, int_w3, int_b3,
                                   inter_out, 1);
    k_head<<<G_, 128, 0, stream>>>(comb, aff_w1, aff_b1, aff_w2, aff_b2, aff_w3, aff_b3,
                                   aff_out, 0);
    k_gemm128<false, true><<<(N_ + 31) / 32, 256, 0, stream>>>(
        h_buf, Wc, bc, attn_out, nullptr, nullptr, nullptr, nullptr, N_);
}

// Round 4
// 493.271 us; speedup vs baseline: 4.7508x; 1.2301x over previous
//
#include <hip/hip_runtime.h>
#include <hip/hip_bf16.h>

typedef float v4 __attribute__((ext_vector_type(4)));

// h = relu(x @ embed_w + embed_b); x: [N,20], w: [20,128]
__global__ __launch_bounds__(256) void k_embed(const float* __restrict__ x,
                                               const float* __restrict__ w,
                                               const float* __restrict__ b,
                                               float* __restrict__ h, int n) {
    int idx = blockIdx.x * 256 + threadIdx.x;
    if (idx >= n * 128) return;
    int node = idx >> 7, j = idx & 127;
    float acc = b[j];
#pragma unroll
    for (int k = 0; k < 20; ++k) acc += x[node * 20 + k] * w[k * 128 + j];
    h[idx] = fmaxf(acc, 0.f);
}

// ---------------- CSR build (once; edge_index is layer-invariant) ----------------

__global__ __launch_bounds__(256) void k_csr_zero(int* __restrict__ cnt,
                                                  int* __restrict__ cursor, int n) {
    int i = blockIdx.x * 256 + threadIdx.x;
    if (i < n) { cnt[i] = 0; cursor[i] = 0; }
}

__global__ __launch_bounds__(256) void k_hist(const int* __restrict__ ei,
                                              int* __restrict__ cnt, int E_) {
    int e = blockIdx.x * 256 + threadIdx.x;
    if (e < E_) atomicAdd(&cnt[ei[E_ + e]], 1);
}

__global__ __launch_bounds__(256) void k_scan_local(const int* __restrict__ cnt,
                                                    int* __restrict__ ptr,
                                                    int* __restrict__ bsum, int n) {
    __shared__ int s[256];
    int t = threadIdx.x, i = blockIdx.x * 256 + t;
    int v = (i < n) ? cnt[i] : 0;
    s[t] = v;
    __syncthreads();
    for (int o = 1; o < 256; o <<= 1) {
        int x = (t >= o) ? s[t - o] : 0;
        __syncthreads();
        s[t] += x;
        __syncthreads();
    }
    if (i < n) ptr[i] = s[t] - v;  // exclusive within block
    if (t == 255) bsum[blockIdx.x] = s[255];
}

__global__ __launch_bounds__(256) void k_scan_bsum(int* __restrict__ bsum, int nb) {
    __shared__ int s[256];
    int t = threadIdx.x;
    int v = (t < nb) ? bsum[t] : 0;
    s[t] = v;
    __syncthreads();
    for (int o = 1; o < 256; o <<= 1) {
        int x = (t >= o) ? s[t - o] : 0;
        __syncthreads();
        s[t] += x;
        __syncthreads();
    }
    if (t < nb) bsum[t] = s[t] - v;  // exclusive
}

__global__ __launch_bounds__(256) void k_scan_add(int* __restrict__ ptr,
                                                  const int* __restrict__ bsum,
                                                  int n, int E_) {
    int i = blockIdx.x * 256 + threadIdx.x;
    if (i < n) ptr[i] += bsum[i >> 8];
    if (i == 0) ptr[n] = E_;
}

// scatter edges into dst-sorted CSR order: esrc_s[p] = src, ea_s[p] = edge_attr[e]
__global__ __launch_bounds__(256) void k_scatter(const int* __restrict__ ei,
                                                 const float* __restrict__ edge_attr,
                                                 const int* __restrict__ ptr,
                                                 int* __restrict__ cursor,
                                                 int* __restrict__ esrc_s,
                                                 float* __restrict__ ea_s, int E_) {
    int e = blockIdx.x * 256 + threadIdx.x;
    if (e >= E_) return;
    int d = ei[E_ + e];
    int p = ptr[d] + atomicAdd(&cursor[d], 1);
    esrc_s[p] = ei[e];
    ((v4*)ea_s)[p] = ((const v4*)edge_attr)[e];
}

// ---------------- GEMM [nn,128] x [128,128] ----------------

template <bool ALPHAS, bool BIAS>
__global__ __launch_bounds__(256) void k_gemm128(
    const float* __restrict__ in, const float* __restrict__ W,
    const float* __restrict__ bias, float* __restrict__ out,
    const float* __restrict__ avec_src, const float* __restrict__ avec_dst,
    float* __restrict__ asrc, float* __restrict__ adst, int nn) {
    __shared__ float Ws[128 * 128];
    __shared__ float rowbuf[32][128];
    int tid = threadIdx.x;
    const v4* W4 = (const v4*)W;
    v4* Ws4 = (v4*)Ws;
    for (int i = tid; i < 4096; i += 256) Ws4[i] = W4[i];
    int row0 = blockIdx.x * 32;
    for (int i = tid; i < 1024; i += 256) {
        int r = i >> 5, c4 = i & 31;
        int gr = row0 + r;
        v4 v = {0.f, 0.f, 0.f, 0.f};
        if (gr < nn) v = ((const v4*)in)[(size_t)gr * 32 + c4];
        ((v4*)&rowbuf[r][0])[c4] = v;
    }
    __syncthreads();
    int rg = tid >> 5;   // rows rg*4..rg*4+3
    int cg = tid & 31;   // cols cg*4..cg*4+3
    float acc[4][4] = {};
    for (int k = 0; k < 128; k += 4) {
        v4 wv[4], rv[4];
#pragma unroll
        for (int kk = 0; kk < 4; ++kk) wv[kk] = *(const v4*)&Ws[(k + kk) * 128 + cg * 4];
#pragma unroll
        for (int r = 0; r < 4; ++r) rv[r] = *(const v4*)&rowbuf[rg * 4 + r][k];
#pragma unroll
        for (int r = 0; r < 4; ++r)
#pragma unroll
            for (int kk = 0; kk < 4; ++kk) {
#pragma unroll
                for (int c = 0; c < 4; ++c) acc[r][c] += rv[r][kk] * wv[kk][c];
            }
    }
#pragma unroll
    for (int r = 0; r < 4; ++r) {
        int gr = row0 + rg * 4 + r;
        v4 o = {acc[r][0], acc[r][1], acc[r][2], acc[r][3]};
        if (BIAS) {
#pragma unroll
            for (int c = 0; c < 4; ++c) o[c] += bias[cg * 4 + c];
        }
        if (gr < nn) *(v4*)&out[(size_t)gr * 128 + cg * 4] = o;
    }
    if (ALPHAS) {
        int head = cg >> 3;
#pragma unroll
        for (int r = 0; r < 4; ++r) {
            int gr = row0 + rg * 4 + r;
            float ps = 0.f, pd = 0.f;
#pragma unroll
            for (int c = 0; c < 4; ++c) {
                float hv = acc[r][c];
                ps += hv * avec_src[cg * 4 + c];
                pd += hv * avec_dst[cg * 4 + c];
            }
            ps += __shfl_xor(ps, 1); ps += __shfl_xor(ps, 2); ps += __shfl_xor(ps, 4);
            pd += __shfl_xor(pd, 1); pd += __shfl_xor(pd, 2); pd += __shfl_xor(pd, 4);
            if ((cg & 7) == 0 && gr < nn) {
                asrc[gr * 4 + head] = ps;
                adst[gr * 4 + head] = pd;
            }
        }
    }
}

// Wc = Vw @ Ow ; bc = vb @ Ow + ob   (seq_len=1 MHA reduces to one affine map)
__global__ __launch_bounds__(128) void k_fuse_vo(const float* __restrict__ vw,
                                                 const float* __restrict__ vb,
                                                 const float* __restrict__ ow,
                                                 const float* __restrict__ ob,
                                                 float* __restrict__ Wc,
                                                 float* __restrict__ bc) {
    int k = blockIdx.x, j = threadIdx.x;
    float acc = 0.f;
    for (int m = 0; m < 128; ++m) acc += vw[k * 128 + m] * ow[m * 128 + j];
    Wc[k * 128 + j] = acc;
    if (k == 0) {
        float b = ob[j];
        for (int m = 0; m < 128; ++m) b += vb[m] * ow[m * 128 + j];
        bc[j] = b;
    }
}

// wave per node, 4 edge-groups x 16 lanes x 8 channels.
// Computes alpha on the fly (softmax without max-shift: shift-invariant, alpha=O(1)),
// aggregates exp-weighted messages, then bias/residual/LN/relu. Single pass, no atomics.
__global__ __launch_bounds__(256) void k_node_agg(
    const float* __restrict__ hl, const int* __restrict__ ptr,
    const int* __restrict__ esrc_s, const float* __restrict__ ea_s,
    const float* __restrict__ asrc, const float* __restrict__ adst,
    const float* __restrict__ edge_w, const float* __restrict__ a_edge,
    const float* __restrict__ bias, const float* __restrict__ lng,
    const float* __restrict__ lnb, float* __restrict__ h, int n) {
    __shared__ float aew[16];  // [k*4 + head]
    int tid = threadIdx.x;
    if (tid < 16) {
        int k = tid >> 2, hh = tid & 3;
        float s = 0.f;
        for (int c = 0; c < 32; ++c) s += edge_w[k * 128 + hh * 32 + c] * a_edge[hh * 32 + c];
        aew[tid] = s;
    }
    __syncthreads();

    int node = blockIdx.x * 4 + (tid >> 6);
    if (node >= n) return;
    int lane = tid & 63;
    int g = lane >> 4;        // edge group 0..3
    int l16 = lane & 15;
    int c0 = l16 * 8;         // 8 channels per lane
    int hh = l16 >> 2;        // head of these channels

    float aewc0 = aew[hh], aewc1 = aew[4 + hh], aewc2 = aew[8 + hh], aewc3 = aew[12 + hh];
    int start = ptr[node], end = ptr[node + 1];
    float adn = adst[(size_t)node * 4 + hh];

    float acc[8] = {};
    float den = 0.f;
    int p = start + g;
    int srcp = (p < end) ? esrc_s[p] : 0;
    for (; p < end; p += 4) {
        int srcn = (p + 4 < end) ? esrc_s[p + 4] : 0;
        v4 ea = ((const v4*)ea_s)[p];
        float a = asrc[(size_t)srcp * 4 + hh] + adn +
                  ea[0] * aewc0 + ea[1] * aewc1 + ea[2] * aewc2 + ea[3] * aewc3;
        a = a > 0.f ? a : 0.2f * a;
        float ex = __expf(a);
        den += ex;
        v4 h0 = *(const v4*)&hl[(size_t)srcp * 128 + c0];
        v4 h1 = *(const v4*)&hl[(size_t)srcp * 128 + c0 + 4];
#pragma unroll
        for (int j = 0; j < 4; ++j) acc[j] += ex * h0[j];
#pragma unroll
        for (int j = 0; j < 4; ++j) acc[4 + j] += ex * h1[j];
        srcp = srcn;
    }

    // combine the 4 edge groups (lanes l16, l16+16, l16+32, l16+48 share channels)
#pragma unroll
    for (int j = 0; j < 8; ++j) {
        acc[j] += __shfl_xor(acc[j], 16);
        acc[j] += __shfl_xor(acc[j], 32);
    }
    den += __shfl_xor(den, 16);
    den += __shfl_xor(den, 32);

    float inv = 1.f / (den + 1e-16f);
    v4 r0 = *(const v4*)&h[(size_t)node * 128 + c0];
    v4 r1 = *(const v4*)&h[(size_t)node * 128 + c0 + 4];
    v4 b0 = *(const v4*)&bias[c0];
    v4 b1 = *(const v4*)&bias[c0 + 4];
    float v[8];
#pragma unroll
    for (int j = 0; j < 4; ++j) v[j] = acc[j] * inv + b0[j] + r0[j];
#pragma unroll
    for (int j = 0; j < 4; ++j) v[4 + j] = acc[4 + j] * inv + b1[j] + r1[j];

    float s = 0.f, sq = 0.f;
#pragma unroll
    for (int j = 0; j < 8; ++j) { s += v[j]; sq += v[j] * v[j]; }
#pragma unroll
    for (int o = 1; o < 16; o <<= 1) { s += __shfl_xor(s, o); sq += __shfl_xor(sq, o); }
    float mu = s * (1.f / 128.f);
    float var = sq * (1.f / 128.f) - mu * mu;
    float rs = rsqrtf(var + 1e-5f);

    if (g == 0) {
        v4 g0 = *(const v4*)&lng[c0];
        v4 g1 = *(const v4*)&lng[c0 + 4];
        v4 lb0 = *(const v4*)&lnb[c0];
        v4 lb1 = *(const v4*)&lnb[c0 + 4];
        v4 o0, o1;
#pragma unroll
        for (int j = 0; j < 4; ++j) o0[j] = fmaxf((v[j] - mu) * rs * g0[j] + lb0[j], 0.f);
#pragma unroll
        for (int j = 0; j < 4; ++j) o1[j] = fmaxf((v[4 + j] - mu) * rs * g1[j] + lb1[j], 0.f);
        *(v4*)&h[(size_t)node * 128 + c0] = o0;
        *(v4*)&h[(size_t)node * 128 + c0 + 4] = o1;
    }
}

__device__ __forceinline__ int lower_bound_i(const int* a, int n, int key) {
    int lo = 0, hi = n;
    while (lo < hi) {
        int mid = (lo + hi) >> 1;
        if (a[mid] < key) lo = mid + 1; else hi = mid;
    }
    return lo;
}

// ---------------- two-stage pooling ----------------

__global__ __launch_bounds__(256) void k_pool_zero(float* __restrict__ gsum,
                                                   float* __restrict__ gmax, int g128) {
    int i = blockIdx.x * 256 + threadIdx.x;
    if (i < g128) { gsum[i] = 0.f; gmax[i] = 0.f; }
}

// 2048 blocks; each owns a contiguous node slice. batch sorted; h >= 0 (relu),
// so float atomicMax == int atomicMax on the bit pattern.
__global__ __launch_bounds__(256) void k_pool_part(const float* __restrict__ h,
                                                   const int* __restrict__ batch,
                                                   float* __restrict__ gsum,
                                                   float* __restrict__ gmax,
                                                   int n, int chunk) {
    int start = blockIdx.x * chunk;
    int end = min(start + chunk, n);
    if (start >= end) return;
    int j = threadIdx.x & 127, half = threadIdx.x >> 7;
    float s = 0.f, mx = 0.f;
    int curg = -1;
    for (int node = start + half; node < end; node += 2) {
        int g = batch[node];
        if (g != curg) {
            if (curg >= 0) {
                atomicAdd(&gsum[curg * 128 + j], s);
                atomicMax((int*)&gmax[curg * 128 + j], __float_as_int(mx));
            }
            curg = g; s = 0.f; mx = 0.f;
        }
        float v = h[(size_t)node * 128 + j];
        s += v;
        mx = fmaxf(mx, v);
    }
    if (curg >= 0) {
        atomicAdd(&gsum[curg * 128 + j], s);
        atomicMax((int*)&gmax[curg * 128 + j], __float_as_int(mx));
    }
}

__global__ __launch_bounds__(128) void k_pool_fin(const float* __restrict__ gsum,
                                                  const float* __restrict__ gmax,
                                                  const int* __restrict__ batch,
                                                  float* __restrict__ comb, int n) {
    int g = blockIdx.x, j = threadIdx.x;
    int start = lower_bound_i(batch, n, g);
    int end = lower_bound_i(batch, n, g + 1);
    float cnt = (float)(end - start);
    comb[g * 384 + j] = gsum[g * 128 + j] / cnt;
    comb[g * 384 + 128 + j] = gmax[g * 128 + j];
}

__global__ __launch_bounds__(128) void k_had(const float* __restrict__ hf,
                                             const float* __restrict__ w1,
                                             const float* __restrict__ b1,
                                             const float* __restrict__ w2,
                                             const float* __restrict__ b2,
                                             float* __restrict__ comb) {
    __shared__ float h1[128];
    int g = blockIdx.x, j = threadIdx.x;
    float acc = b1[j];
#pragma unroll
    for (int k = 0; k < 12; ++k) acc += hf[g * 12 + k] * w1[k * 128 + j];
    h1[j] = fmaxf(acc, 0.f);
    __syncthreads();
    float a2 = b2[j];
    for (int k = 0; k < 128; ++k) a2 += h1[k] * w2[k * 128 + j];
    comb[g * 384 + 256 + j] = a2;
}

__global__ __launch_bounds__(128) void k_head(const float* __restrict__ comb,
                                              const float* __restrict__ w1,
                                              const float* __restrict__ b1,
                                              const float* __restrict__ w2,
                                              const float* __restrict__ b2,
                                              const float* __restrict__ w3,
                                              const float* __restrict__ b3,
                                              float* __restrict__ outp, int sigm) {
    __shared__ float cs[384];
    __shared__ float z1[128];
    __shared__ float z2[64];
    int g = blockIdx.x, j = threadIdx.x;
    for (int k = j; k < 384; k += 128) cs[k] = comb[g * 384 + k];
    __syncthreads();
    float acc = b1[j];
    for (int k = 0; k < 384; ++k) acc += cs[k] * w1[k * 128 + j];
    z1[j] = fmaxf(acc, 0.f);
    __syncthreads();
    if (j < 64) {
        float a2 = b2[j];
        for (int k = 0; k < 128; ++k) a2 += z1[k] * w2[k * 64 + j];
        z2[j] = fmaxf(a2, 0.f);
    }
    __syncthreads();
    if (j == 0) {
        float a3 = b3[0];
        for (int k = 0; k < 64; ++k) a3 += z2[k] * w3[k];
        if (sigm) a3 = 1.f / (1.f + __expf(-a3));
        outp[g] = a3;
    }
}

extern "C" void kernel_launch(void* const* d_in, const int* in_sizes, int n_in,
                              void* d_out, int out_size, void* d_ws, size_t ws_size,
                              hipStream_t stream) {
    const float* x = (const float*)d_in[0];
    const float* edge_attr = (const float*)d_in[1];
    const float* haddock = (const float*)d_in[2];
    const int* ei = (const int*)d_in[3];
    const int* batch = (const int*)d_in[4];
    const float* embed_w = (const float*)d_in[5];
    const float* embed_b = (const float*)d_in[6];
    const float* gat_lin_w = (const float*)d_in[7];
    const float* gat_att_src = (const float*)d_in[8];
    const float* gat_att_dst = (const float*)d_in[9];
    const float* gat_edge_w = (const float*)d_in[10];
    const float* gat_att_edge = (const float*)d_in[11];
    const float* gat_bias = (const float*)d_in[12];
    const float* ln_g = (const float*)d_in[13];
    const float* ln_b = (const float*)d_in[14];
    const float* had_w1 = (const float*)d_in[15];
    const float* had_b1 = (const float*)d_in[16];
    const float* had_w2 = (const float*)d_in[17];
    const float* had_b2 = (const float*)d_in[18];
    const float* int_w1 = (const float*)d_in[19];
    const float* int_b1 = (const float*)d_in[20];
    const float* int_w2 = (const float*)d_in[21];
    const float* int_b2 = (const float*)d_in[22];
    const float* int_w3 = (const float*)d_in[23];
    const float* int_b3 = (const float*)d_in[24];
    const float* aff_w1 = (const float*)d_in[25];
    const float* aff_b1 = (const float*)d_in[26];
    const float* aff_w2 = (const float*)d_in[27];
    const float* aff_b2 = (const float*)d_in[28];
    const float* aff_w3 = (const float*)d_in[29];
    const float* aff_b3 = (const float*)d_in[30];
    const float* mha_v_w = (const float*)d_in[31];
    const float* mha_v_b = (const float*)d_in[32];
    const float* mha_o_w = (const float*)d_in[33];
    const float* mha_o_b = (const float*)d_in[34];

    const int N_ = in_sizes[0] / 20;
    const int E_ = in_sizes[1] / 4;
    const int G_ = in_sizes[2] / 12;

    float* out_f = (float*)d_out;
    float* inter_out = out_f;
    float* aff_out = out_f + G_;
    float* attn_out = out_f + 2 * G_;
    float* h_buf = attn_out + (size_t)N_ * 128;
    float* hl = attn_out;  // scratch during GAT layers

    // workspace layout
    int* cnt = (int*)d_ws;
    int* cursor = cnt + N_;
    int* ptr = cursor + N_;              // N_+1
    int* bsum = ptr + N_ + 1;            // 256
    int* esrc_s = bsum + 256;            // E_
    float* ea_s = (float*)(esrc_s + E_); // E_*4
    float* asrc = ea_s + (size_t)E_ * 4; // N_*4
    float* adst = asrc + (size_t)N_ * 4; // N_*4
    float* comb = adst + (size_t)N_ * 4; // G_*384
    float* gsum = comb + (size_t)G_ * 384;    // G_*128
    float* gmax = gsum + (size_t)G_ * 128;    // G_*128
    float* Wc = gmax + (size_t)G_ * 128;      // 128*128
    float* bc = Wc + 128 * 128;               // 128

    const int nb_scan = (N_ + 255) / 256;
    const int POOL_BLOCKS = 2048;
    const int chunk = (N_ + POOL_BLOCKS - 1) / POOL_BLOCKS;

    k_embed<<<(N_ * 128 + 255) / 256, 256, 0, stream>>>(x, embed_w, embed_b, h_buf, N_);

    // CSR build (once)
    k_csr_zero<<<nb_scan, 256, 0, stream>>>(cnt, cursor, N_);
    k_hist<<<(E_ + 255) / 256, 256, 0, stream>>>(ei, cnt, E_);
    k_scan_local<<<nb_scan, 256, 0, stream>>>(cnt, ptr, bsum, N_);
    k_scan_bsum<<<1, 256, 0, stream>>>(bsum, nb_scan);
    k_scan_add<<<nb_scan, 256, 0, stream>>>(ptr, bsum, N_, E_);
    k_scatter<<<(E_ + 255) / 256, 256, 0, stream>>>(ei, edge_attr, ptr, cursor,
                                                    esrc_s, ea_s, E_);

    // MHA algebraic fusion (independent of the layer loop)
    k_fuse_vo<<<128, 128, 0, stream>>>(mha_v_w, mha_v_b, mha_o_w, mha_o_b, Wc, bc);
    k_pool_zero<<<(G_ * 128 + 255) / 256, 256, 0, stream>>>(gsum, gmax, G_ * 128);

    for (int i = 0; i < 3; ++i) {
        k_gemm128<true, false><<<(N_ + 31) / 32, 256, 0, stream>>>(
            h_buf, gat_lin_w + (size_t)i * 16384, nullptr, hl,
            gat_att_src + i * 128, gat_att_dst + i * 128, asrc, adst, N_);
        k_node_agg<<<(N_ + 3) / 4, 256, 0, stream>>>(
            hl, ptr, esrc_s, ea_s, asrc, adst,
            gat_edge_w + (size_t)i * 512, gat_att_edge + i * 128,
            gat_bias + i * 128, ln_g + i * 128, ln_b + i * 128, h_buf, N_);
    }

    k_pool_part<<<POOL_BLOCKS, 256, 0, stream>>>(h_buf, batch, gsum, gmax, N_, chunk);
    k_pool_fin<<<G_, 128, 0, stream>>>(gsum, gmax, batch, comb, N_);
    k_had<<<G_, 128, 0, stream>>>(haddock, had_w1, had_b1, had_w2, had_b2, comb);
    k_head<<<G_, 128, 0, stream>>>(comb, int_w1, int_b1, int_w2, int_b2, int_w3, int_b3,
                                   inter_out, 1);
    k_head<<<G_, 128, 0, stream>>>(comb, aff_w1, aff_b1, aff_w2, aff_b2, aff_w3, aff_b3,
                                   aff_out, 0);
    k_gemm128<false, true><<<(N_ + 31) / 32, 256, 0, stream>>>(
        h_buf, Wc, bc, attn_out, nullptr, nullptr, nullptr, nullptr, N_);
}

// Round 5
// 404.830 us; speedup vs baseline: 5.7887x; 1.2185x over previous
//
#include <hip/hip_runtime.h>
#include <hip/hip_bf16.h>

typedef float v4 __attribute__((ext_vector_type(4)));
typedef float f32x4 __attribute__((ext_vector_type(4)));
typedef short bf16x8 __attribute__((ext_vector_type(8)));
typedef unsigned short us8 __attribute__((ext_vector_type(8)));

__device__ __forceinline__ unsigned short f2bf(float f) {
    unsigned u = __float_as_uint(f);
    u = (u + 0x7FFFu + ((u >> 16) & 1u)) >> 16;
    return (unsigned short)u;
}
__device__ __forceinline__ float bf2f(unsigned short s) {
    return __uint_as_float(((unsigned)s) << 16);
}

// h = relu(x @ embed_w + embed_b); writes f32 h and bf16 h_bf
__global__ __launch_bounds__(256) void k_embed(const float* __restrict__ x,
                                               const float* __restrict__ w,
                                               const float* __restrict__ b,
                                               float* __restrict__ h,
                                               unsigned short* __restrict__ h_bf, int n) {
    int idx = blockIdx.x * 256 + threadIdx.x;
    if (idx >= n * 128) return;
    int node = idx >> 7, j = idx & 127;
    float acc = b[j];
#pragma unroll
    for (int k = 0; k < 20; ++k) acc += x[node * 20 + k] * w[k * 128 + j];
    float r = fmaxf(acc, 0.f);
    h[idx] = r;
    h_bf[idx] = f2bf(r);
}

// ---------------- CSR build (once; edge_index is layer-invariant) ----------------

__global__ __launch_bounds__(256) void k_csr_zero(int* __restrict__ cnt,
                                                  int* __restrict__ cursor, int n) {
    int i = blockIdx.x * 256 + threadIdx.x;
    if (i < n) { cnt[i] = 0; cursor[i] = 0; }
}

__global__ __launch_bounds__(256) void k_hist(const int* __restrict__ ei,
                                              int* __restrict__ cnt, int E_) {
    int e = blockIdx.x * 256 + threadIdx.x;
    if (e < E_) atomicAdd(&cnt[ei[E_ + e]], 1);
}

__global__ __launch_bounds__(256) void k_scan_local(const int* __restrict__ cnt,
                                                    int* __restrict__ ptr,
                                                    int* __restrict__ bsum, int n) {
    __shared__ int s[256];
    int t = threadIdx.x, i = blockIdx.x * 256 + t;
    int v = (i < n) ? cnt[i] : 0;
    s[t] = v;
    __syncthreads();
    for (int o = 1; o < 256; o <<= 1) {
        int x = (t >= o) ? s[t - o] : 0;
        __syncthreads();
        s[t] += x;
        __syncthreads();
    }
    if (i < n) ptr[i] = s[t] - v;
    if (t == 255) bsum[blockIdx.x] = s[255];
}

__global__ __launch_bounds__(256) void k_scan_bsum(int* __restrict__ bsum, int nb) {
    __shared__ int s[256];
    int t = threadIdx.x;
    int v = (t < nb) ? bsum[t] : 0;
    s[t] = v;
    __syncthreads();
    for (int o = 1; o < 256; o <<= 1) {
        int x = (t >= o) ? s[t - o] : 0;
        __syncthreads();
        s[t] += x;
        __syncthreads();
    }
    if (t < nb) bsum[t] = s[t] - v;
}

__global__ __launch_bounds__(256) void k_scan_add(int* __restrict__ ptr,
                                                  const int* __restrict__ bsum,
                                                  int n, int E_) {
    int i = blockIdx.x * 256 + threadIdx.x;
    if (i < n) ptr[i] += bsum[i >> 8];
    if (i == 0) ptr[n] = E_;
}

__global__ __launch_bounds__(256) void k_scatter(const int* __restrict__ ei,
                                                 const float* __restrict__ edge_attr,
                                                 const int* __restrict__ ptr,
                                                 int* __restrict__ cursor,
                                                 int* __restrict__ esrc_s,
                                                 float* __restrict__ ea_s, int E_) {
    int e = blockIdx.x * 256 + threadIdx.x;
    if (e >= E_) return;
    int d = ei[E_ + e];
    int p = ptr[d] + atomicAdd(&cursor[d], 1);
    esrc_s[p] = ei[e];
    ((v4*)ea_s)[p] = ((const v4*)edge_attr)[e];
}

// Wc = Vw @ Ow ; bc = vb @ Ow + ob   (seq_len=1 MHA reduces to one affine map)
__global__ __launch_bounds__(128) void k_fuse_vo(const float* __restrict__ vw,
                                                 const float* __restrict__ vb,
                                                 const float* __restrict__ ow,
                                                 const float* __restrict__ ob,
                                                 float* __restrict__ Wc,
                                                 float* __restrict__ bc) {
    int k = blockIdx.x, j = threadIdx.x;
    float acc = 0.f;
    for (int m = 0; m < 128; ++m) acc += vw[k * 128 + m] * ow[m * 128 + j];
    Wc[k * 128 + j] = acc;
    if (k == 0) {
        float b = ob[j];
        for (int m = 0; m < 128; ++m) b += vb[m] * ow[m * 128 + j];
        bc[j] = b;
    }
}

// Pack W[128][128] (f32) into bf16 MFMA B-fragment order:
// Bpack[m][c*4+kb][lane][e] = bf16(W[kb*32 + (lane>>4)*8 + e][c*16 + (lane&15)])
__global__ __launch_bounds__(256) void k_pack_w(const float* __restrict__ gat_lin_w,
                                                const float* __restrict__ Wc,
                                                unsigned short* __restrict__ Bpack) {
    int m = blockIdx.y;
    const float* W = (m < 3) ? (gat_lin_w + (size_t)m * 16384) : Wc;
    int idx = blockIdx.x * 256 + threadIdx.x;  // 0..16383
    int e = idx & 7, l = (idx >> 3) & 63, kb = (idx >> 9) & 3, c = idx >> 11;
    int k = kb * 32 + ((l >> 4) << 3) + e;
    int col = c * 16 + (l & 15);
    Bpack[(size_t)m * 16384 + idx] = f2bf(W[k * 128 + col]);
}

// ---------------- MFMA GEMM [nn,128](bf16) x [128,128](packed bf16) ----------------
// block = 256 thr = 4 waves; wave w owns rows row0+16w..+15; 8 col-tiles of 16.
template <bool ALPHAS, bool OUTF32>
__global__ __launch_bounds__(256) void k_gemm_mfma(
    const unsigned short* __restrict__ A,     // [Npad][128] bf16
    const unsigned short* __restrict__ Bpack, // [32][64][8] bf16
    const float* __restrict__ bias,           // OUTF32
    unsigned short* __restrict__ out_bf,      // !OUTF32
    float* __restrict__ out_f32,              // OUTF32
    const float* __restrict__ avs, const float* __restrict__ avd,
    float* __restrict__ asrc, float* __restrict__ adst, int nn) {
    __shared__ float lds[64][132];
    int tid = threadIdx.x;
    int w = tid >> 6, l = tid & 63;
    int row0 = blockIdx.x * 64;
    int arow = row0 + w * 16 + (l & 15);
    int koff = (l >> 4) * 8;

    bf16x8 a[4];
#pragma unroll
    for (int kb = 0; kb < 4; ++kb)
        a[kb] = *(const bf16x8*)&A[(size_t)arow * 128 + kb * 32 + koff];

    const bf16x8* bp = (const bf16x8*)Bpack;
    f32x4 acc[8];
#pragma unroll
    for (int c = 0; c < 8; ++c) {
        f32x4 z = {0.f, 0.f, 0.f, 0.f};
        acc[c] = z;
#pragma unroll
        for (int kb = 0; kb < 4; ++kb)
            acc[c] = __builtin_amdgcn_mfma_f32_16x16x32_bf16(a[kb], bp[(c * 4 + kb) * 64 + l],
                                                             acc[c], 0, 0, 0);
    }

    // D layout: col = lane&15, row = (lane>>4)*4 + reg  -> transpose via LDS
    int colb = l & 15;
    int rowb = w * 16 + (l >> 4) * 4;
#pragma unroll
    for (int c = 0; c < 8; ++c)
#pragma unroll
        for (int r = 0; r < 4; ++r)
            lds[rowb + r][c * 16 + colb] = acc[c][r];
    __syncthreads();

    int rl = tid >> 2, q = tid & 3;  // row-local 0..63, quarter 0..3 (= head for alphas)
    int gr = row0 + rl;
    if (gr >= nn) return;
    float v[32];
#pragma unroll
    for (int j = 0; j < 8; ++j)
        *(f32x4*)&v[j * 4] = *(const f32x4*)&lds[rl][q * 32 + j * 4];

    if (ALPHAS) {
        float ps = 0.f, pd = 0.f;
#pragma unroll
        for (int j = 0; j < 32; ++j) {
            ps += v[j] * avs[q * 32 + j];
            pd += v[j] * avd[q * 32 + j];
        }
        asrc[(size_t)gr * 4 + q] = ps;
        adst[(size_t)gr * 4 + q] = pd;
    }
    if (OUTF32) {
#pragma unroll
        for (int j = 0; j < 32; ++j) v[j] += bias[q * 32 + j];
#pragma unroll
        for (int j = 0; j < 8; ++j)
            *(f32x4*)&out_f32[(size_t)gr * 128 + q * 32 + j * 4] = *(f32x4*)&v[j * 4];
    } else {
        us8 o0, o1;
#pragma unroll
        for (int j = 0; j < 8; ++j) o0[j] = f2bf(v[j]);
#pragma unroll
        for (int j = 0; j < 8; ++j) o1[j] = f2bf(v[8 + j]);
        *(us8*)&out_bf[(size_t)gr * 128 + q * 32] = o0;
        *(us8*)&out_bf[(size_t)gr * 128 + q * 32 + 8] = o1;
        us8 o2, o3;
#pragma unroll
        for (int j = 0; j < 8; ++j) o2[j] = f2bf(v[16 + j]);
#pragma unroll
        for (int j = 0; j < 8; ++j) o3[j] = f2bf(v[24 + j]);
        *(us8*)&out_bf[(size_t)gr * 128 + q * 32 + 16] = o2;
        *(us8*)&out_bf[(size_t)gr * 128 + q * 32 + 24] = o3;
    }
}

// wave per node, 4 edge-groups x 16 lanes x 8 channels; bf16 message gathers.
__global__ __launch_bounds__(256) void k_node_agg(
    const unsigned short* __restrict__ hl_bf, const int* __restrict__ ptr,
    const int* __restrict__ esrc_s, const float* __restrict__ ea_s,
    const float* __restrict__ asrc, const float* __restrict__ adst,
    const float* __restrict__ edge_w, const float* __restrict__ a_edge,
    const float* __restrict__ bias, const float* __restrict__ lng,
    const float* __restrict__ lnb, float* __restrict__ h,
    unsigned short* __restrict__ h_bf, int n) {
    __shared__ float aew[16];  // [k*4 + head]
    int tid = threadIdx.x;
    if (tid < 16) {
        int k = tid >> 2, hh = tid & 3;
        float s = 0.f;
        for (int c = 0; c < 32; ++c) s += edge_w[k * 128 + hh * 32 + c] * a_edge[hh * 32 + c];
        aew[tid] = s;
    }
    __syncthreads();

    int node = blockIdx.x * 4 + (tid >> 6);
    if (node >= n) return;
    int lane = tid & 63;
    int g = lane >> 4;
    int l16 = lane & 15;
    int c0 = l16 * 8;
    int hh = l16 >> 2;

    float aewc0 = aew[hh], aewc1 = aew[4 + hh], aewc2 = aew[8 + hh], aewc3 = aew[12 + hh];
    int start = ptr[node], end = ptr[node + 1];
    float adn = adst[(size_t)node * 4 + hh];

    float acc[8] = {};
    float den = 0.f;
    int p = start + g;
    int srcp = (p < end) ? esrc_s[p] : 0;
    for (; p < end; p += 4) {
        int srcn = (p + 4 < end) ? esrc_s[p + 4] : 0;
        v4 ea = ((const v4*)ea_s)[p];
        float a = asrc[(size_t)srcp * 4 + hh] + adn +
                  ea[0] * aewc0 + ea[1] * aewc1 + ea[2] * aewc2 + ea[3] * aewc3;
        a = a > 0.f ? a : 0.2f * a;
        float ex = __expf(a);
        den += ex;
        us8 hv = *(const us8*)&hl_bf[(size_t)srcp * 128 + c0];
#pragma unroll
        for (int j = 0; j < 8; ++j) acc[j] += ex * bf2f(hv[j]);
        srcp = srcn;
    }

#pragma unroll
    for (int j = 0; j < 8; ++j) {
        acc[j] += __shfl_xor(acc[j], 16);
        acc[j] += __shfl_xor(acc[j], 32);
    }
    den += __shfl_xor(den, 16);
    den += __shfl_xor(den, 32);

    float inv = 1.f / (den + 1e-16f);
    v4 r0 = *(const v4*)&h[(size_t)node * 128 + c0];
    v4 r1 = *(const v4*)&h[(size_t)node * 128 + c0 + 4];
    v4 b0 = *(const v4*)&bias[c0];
    v4 b1 = *(const v4*)&bias[c0 + 4];
    float v[8];
#pragma unroll
    for (int j = 0; j < 4; ++j) v[j] = acc[j] * inv + b0[j] + r0[j];
#pragma unroll
    for (int j = 0; j < 4; ++j) v[4 + j] = acc[4 + j] * inv + b1[j] + r1[j];

    float s = 0.f, sq = 0.f;
#pragma unroll
    for (int j = 0; j < 8; ++j) { s += v[j]; sq += v[j] * v[j]; }
#pragma unroll
    for (int o = 1; o < 16; o <<= 1) { s += __shfl_xor(s, o); sq += __shfl_xor(sq, o); }
    float mu = s * (1.f / 128.f);
    float var = sq * (1.f / 128.f) - mu * mu;
    float rs = rsqrtf(var + 1e-5f);

    if (g == 0) {
        v4 g0 = *(const v4*)&lng[c0];
        v4 g1 = *(const v4*)&lng[c0 + 4];
        v4 lb0 = *(const v4*)&lnb[c0];
        v4 lb1 = *(const v4*)&lnb[c0 + 4];
        v4 o0, o1;
#pragma unroll
        for (int j = 0; j < 4; ++j) o0[j] = fmaxf((v[j] - mu) * rs * g0[j] + lb0[j], 0.f);
#pragma unroll
        for (int j = 0; j < 4; ++j) o1[j] = fmaxf((v[4 + j] - mu) * rs * g1[j] + lb1[j], 0.f);
        *(v4*)&h[(size_t)node * 128 + c0] = o0;
        *(v4*)&h[(size_t)node * 128 + c0 + 4] = o1;
        us8 ob;
#pragma unroll
        for (int j = 0; j < 4; ++j) ob[j] = f2bf(o0[j]);
#pragma unroll
        for (int j = 0; j < 4; ++j) ob[4 + j] = f2bf(o1[j]);
        *(us8*)&h_bf[(size_t)node * 128 + c0] = ob;
    }
}

__device__ __forceinline__ int lower_bound_i(const int* a, int n, int key) {
    int lo = 0, hi = n;
    while (lo < hi) {
        int mid = (lo + hi) >> 1;
        if (a[mid] < key) lo = mid + 1; else hi = mid;
    }
    return lo;
}

// ---------------- two-stage pooling ----------------

__global__ __launch_bounds__(256) void k_pool_zero(float* __restrict__ gsum,
                                                   float* __restrict__ gmax, int g128) {
    int i = blockIdx.x * 256 + threadIdx.x;
    if (i < g128) { gsum[i] = 0.f; gmax[i] = 0.f; }
}

__global__ __launch_bounds__(256) void k_pool_part(const float* __restrict__ h,
                                                   const int* __restrict__ batch,
                                                   float* __restrict__ gsum,
                                                   float* __restrict__ gmax,
                                                   int n, int chunk) {
    int start = blockIdx.x * chunk;
    int end = min(start + chunk, n);
    if (start >= end) return;
    int j = threadIdx.x & 127, half = threadIdx.x >> 7;
    float s = 0.f, mx = 0.f;
    int curg = -1;
    for (int node = start + half; node < end; node += 2) {
        int g = batch[node];
        if (g != curg) {
            if (curg >= 0) {
                atomicAdd(&gsum[curg * 128 + j], s);
                atomicMax((int*)&gmax[curg * 128 + j], __float_as_int(mx));
            }
            curg = g; s = 0.f; mx = 0.f;
        }
        float v = h[(size_t)node * 128 + j];
        s += v;
        mx = fmaxf(mx, v);
    }
    if (curg >= 0) {
        atomicAdd(&gsum[curg * 128 + j], s);
        atomicMax((int*)&gmax[curg * 128 + j], __float_as_int(mx));
    }
}

__global__ __launch_bounds__(128) void k_pool_fin(const float* __restrict__ gsum,
                                                  const float* __restrict__ gmax,
                                                  const int* __restrict__ batch,
                                                  float* __restrict__ comb, int n) {
    int g = blockIdx.x, j = threadIdx.x;
    int start = lower_bound_i(batch, n, g);
    int end = lower_bound_i(batch, n, g + 1);
    float cnt = (float)(end - start);
    comb[g * 384 + j] = gsum[g * 128 + j] / cnt;
    comb[g * 384 + 128 + j] = gmax[g * 128 + j];
}

__global__ __launch_bounds__(128) void k_had(const float* __restrict__ hf,
                                             const float* __restrict__ w1,
                                             const float* __restrict__ b1,
                                             const float* __restrict__ w2,
                                             const float* __restrict__ b2,
                                             float* __restrict__ comb) {
    __shared__ float h1[128];
    int g = blockIdx.x, j = threadIdx.x;
    float acc = b1[j];
#pragma unroll
    for (int k = 0; k < 12; ++k) acc += hf[g * 12 + k] * w1[k * 128 + j];
    h1[j] = fmaxf(acc, 0.f);
    __syncthreads();
    float a2 = b2[j];
    for (int k = 0; k < 128; ++k) a2 += h1[k] * w2[k * 128 + j];
    comb[g * 384 + 256 + j] = a2;
}

__global__ __launch_bounds__(128) void k_head(const float* __restrict__ comb,
                                              const float* __restrict__ w1,
                                              const float* __restrict__ b1,
                                              const float* __restrict__ w2,
                                              const float* __restrict__ b2,
                                              const float* __restrict__ w3,
                                              const float* __restrict__ b3,
                                              float* __restrict__ outp, int sigm) {
    __shared__ float cs[384];
    __shared__ float z1[128];
    __shared__ float z2[64];
    int g = blockIdx.x, j = threadIdx.x;
    for (int k = j; k < 384; k += 128) cs[k] = comb[g * 384 + k];
    __syncthreads();
    float acc = b1[j];
    for (int k = 0; k < 384; ++k) acc += cs[k] * w1[k * 128 + j];
    z1[j] = fmaxf(acc, 0.f);
    __syncthreads();
    if (j < 64) {
        float a2 = b2[j];
        for (int k = 0; k < 128; ++k) a2 += z1[k] * w2[k * 64 + j];
        z2[j] = fmaxf(a2, 0.f);
    }
    __syncthreads();
    if (j == 0) {
        float a3 = b3[0];
        for (int k = 0; k < 64; ++k) a3 += z2[k] * w3[k];
        if (sigm) a3 = 1.f / (1.f + __expf(-a3));
        outp[g] = a3;
    }
}

extern "C" void kernel_launch(void* const* d_in, const int* in_sizes, int n_in,
                              void* d_out, int out_size, void* d_ws, size_t ws_size,
                              hipStream_t stream) {
    const float* x = (const float*)d_in[0];
    const float* edge_attr = (const float*)d_in[1];
    const float* haddock = (const float*)d_in[2];
    const int* ei = (const int*)d_in[3];
    const int* batch = (const int*)d_in[4];
    const float* embed_w = (const float*)d_in[5];
    const float* embed_b = (const float*)d_in[6];
    const float* gat_lin_w = (const float*)d_in[7];
    const float* gat_att_src = (const float*)d_in[8];
    const float* gat_att_dst = (const float*)d_in[9];
    const float* gat_edge_w = (const float*)d_in[10];
    const float* gat_att_edge = (const float*)d_in[11];
    const float* gat_bias = (const float*)d_in[12];
    const float* ln_g = (const float*)d_in[13];
    const float* ln_b = (const float*)d_in[14];
    const float* had_w1 = (const float*)d_in[15];
    const float* had_b1 = (const float*)d_in[16];
    const float* had_w2 = (const float*)d_in[17];
    const float* had_b2 = (const float*)d_in[18];
    const float* int_w1 = (const float*)d_in[19];
    const float* int_b1 = (const float*)d_in[20];
    const float* int_w2 = (const float*)d_in[21];
    const float* int_b2 = (const float*)d_in[22];
    const float* int_w3 = (const float*)d_in[23];
    const float* int_b3 = (const float*)d_in[24];
    const float* aff_w1 = (const float*)d_in[25];
    const float* aff_b1 = (const float*)d_in[26];
    const float* aff_w2 = (const float*)d_in[27];
    const float* aff_b2 = (const float*)d_in[28];
    const float* aff_w3 = (const float*)d_in[29];
    const float* aff_b3 = (const float*)d_in[30];
    const float* mha_v_w = (const float*)d_in[31];
    const float* mha_v_b = (const float*)d_in[32];
    const float* mha_o_w = (const float*)d_in[33];
    const float* mha_o_b = (const float*)d_in[34];

    const int N_ = in_sizes[0] / 20;
    const int E_ = in_sizes[1] / 4;
    const int G_ = in_sizes[2] / 12;
    const int Npad = (N_ + 63) & ~63;

    float* out_f = (float*)d_out;
    float* inter_out = out_f;
    float* aff_out = out_f + G_;
    float* attn_out = out_f + 2 * G_;
    float* h_buf = attn_out + (size_t)N_ * 128;  // h is the 4th output -> keep f32 here

    // workspace layout (16B-aligned sections)
    unsigned short* h_bf = (unsigned short*)d_ws;              // Npad*128
    unsigned short* hl_bf = h_bf + (size_t)Npad * 128;         // Npad*128
    unsigned short* Bpack = hl_bf + (size_t)Npad * 128;        // 4*16384
    float* ea_s = (float*)(Bpack + 4 * 16384);                 // E*4
    float* Wc = ea_s + (size_t)E_ * 4;                         // 16384
    float* bc = Wc + 16384;                                    // 128
    float* asrc = bc + 128;                                    // N*4
    float* adst = asrc + (size_t)N_ * 4;                       // N*4
    float* gsum = adst + (size_t)N_ * 4;                       // G*128
    float* gmax = gsum + (size_t)G_ * 128;                     // G*128
    float* comb = gmax + (size_t)G_ * 128;                     // G*384
    int* cnt = (int*)(comb + (size_t)G_ * 384);                // N
    int* cursor = cnt + N_;                                    // N
    int* ptr = cursor + N_;                                    // N+4 (padded)
    int* bsum = ptr + N_ + 4;                                  // 256
    int* esrc_s = bsum + 256;                                  // E

    const int nb_scan = (N_ + 255) / 256;
    const int POOL_BLOCKS = 2048;
    const int chunk = (N_ + POOL_BLOCKS - 1) / POOL_BLOCKS;
    const int gemm_blocks = (N_ + 63) / 64;

    k_embed<<<(N_ * 128 + 255) / 256, 256, 0, stream>>>(x, embed_w, embed_b, h_buf, h_bf, N_);

    // CSR build (once)
    k_csr_zero<<<nb_scan, 256, 0, stream>>>(cnt, cursor, N_);
    k_hist<<<(E_ + 255) / 256, 256, 0, stream>>>(ei, cnt, E_);
    k_scan_local<<<nb_scan, 256, 0, stream>>>(cnt, ptr, bsum, N_);
    k_scan_bsum<<<1, 256, 0, stream>>>(bsum, nb_scan);
    k_scan_add<<<nb_scan, 256, 0, stream>>>(ptr, bsum, N_, E_);
    k_scatter<<<(E_ + 255) / 256, 256, 0, stream>>>(ei, edge_attr, ptr, cursor,
                                                    esrc_s, ea_s, E_);

    // MHA algebraic fusion + weight packing (Wc before pack!)
    k_fuse_vo<<<128, 128, 0, stream>>>(mha_v_w, mha_v_b, mha_o_w, mha_o_b, Wc, bc);
    k_pack_w<<<dim3(64, 4), 256, 0, stream>>>(gat_lin_w, Wc, Bpack);
    k_pool_zero<<<(G_ * 128 + 255) / 256, 256, 0, stream>>>(gsum, gmax, G_ * 128);

    for (int i = 0; i < 3; ++i) {
        k_gemm_mfma<true, false><<<gemm_blocks, 256, 0, stream>>>(
            h_bf, Bpack + (size_t)i * 16384, nullptr, hl_bf, nullptr,
            gat_att_src + i * 128, gat_att_dst + i * 128, asrc, adst, N_);
        k_node_agg<<<(N_ + 3) / 4, 256, 0, stream>>>(
            hl_bf, ptr, esrc_s, ea_s, asrc, adst,
            gat_edge_w + (size_t)i * 512, gat_att_edge + i * 128,
            gat_bias + i * 128, ln_g + i * 128, ln_b + i * 128, h_buf, h_bf, N_);
    }

    k_pool_part<<<POOL_BLOCKS, 256, 0, stream>>>(h_buf, batch, gsum, gmax, N_, chunk);
    k_pool_fin<<<G_, 128, 0, stream>>>(gsum, gmax, batch, comb, N_);
    k_had<<<G_, 128, 0, stream>>>(haddock, had_w1, had_b1, had_w2, had_b2, comb);
    k_head<<<G_, 128, 0, stream>>>(comb, int_w1, int_b1, int_w2, int_b2, int_w3, int_b3,
                                   inter_out, 1);
    k_head<<<G_, 128, 0, stream>>>(comb, aff_w1, aff_b1, aff_w2, aff_b2, aff_w3, aff_b3,
                                   aff_out, 0);
    k_gemm_mfma<false, true><<<gemm_blocks, 256, 0, stream>>>(
        h_bf, Bpack + (size_t)3 * 16384, bc, nullptr, attn_out,
        nullptr, nullptr, nullptr, nullptr, N_);
}